// Round 14
// baseline (127.750 us; speedup 1.0000x reference)
//
#include <hip/hip_runtime.h>
#include <hip/hip_fp16.h>
#include <math.h>

#define TDIM 6
#define MDIM 10
#define LDIM 4
#define GIND 14
#define GLOD 10

#define BINSHIFT 8
#define BINSZ 256            // nodes per bin
#define MAXBINS 1024         // supports N up to 262144 (pack limit: src < 2^18)

// ---- fixed-capacity scatter path ----
// v14: grid was the cap, not LDS. 512 blocks on 256 CUs = 2 blocks/CU max
// (r13's LDS slimming freed room for 3 that the grid never used). 1024 blocks
// + CHQ=800 (LDS ~34.8KB) => 4 blocks/CU. Runs shrink 16->8 edges: write amp
// worsens (~+25MB) but kernel runs at 1.8 of 6.3 TB/s, and per-CU
// parallelism doubles.
#define SC2_BLOCKS 1024
#define SC2_THREADS 512
#define SC2_CHQ 800          // quads per chunk (3200 edges)
#define SC2_CHUNKS 2         // QPB <= 1600 quads -> E <= 6.55M
#define SC2_TQ 2             // ceil(SC2_CHQ / SC2_THREADS)
#define OVF_ENT 16384
#define META2 2048           // gcount[1024] + ocur + facc + pad

// ---- accum params ----
#define SC_BLOCK 512
#define SC_EPT 32
#define SC_EPB (SC_BLOCK * SC_EPT)
#define AC_BLOCK 512
#define AC_CAP 8704          // mean 8192 + 5.7 sigma; overflow handled via ovf path
#define AC_EPT 17            // AC_CAP / AC_BLOCK

// ---- split-accum params (v12 winner) ----
#define SRT_HALF 4352        // ceil(AC_CAP/2); 17.4 KB LDS
#define AH_EPT 9             // ceil(SRT_HALF / 512)
#define PB_NODE (BINSZ * TDIM)   // 1536 floats per (bin,half)

// ---------------- small utility ----------------
__global__ void zero32_k(unsigned* __restrict__ p, int n) {
    int i = blockIdx.x * blockDim.x + threadIdx.x;
    if (i < n) p[i] = 0u;
}

__device__ __forceinline__ void add_row4(uint4 r, float& s0, float& s1, float& s2,
                                         float& s3, float& s4, float& s5) {
    float2 a0 = __half22float2(*(__half2*)&r.x);
    float2 a1 = __half22float2(*(__half2*)&r.y);
    float2 a2 = __half22float2(*(__half2*)&r.z);
    s0 += a0.x; s1 += a0.y; s2 += a1.x; s3 += a1.y; s4 += a2.x; s5 += a2.y;
}

// ================= TIER 1: fixed-capacity bins =================

__global__ __launch_bounds__(SC2_THREADS) void scat2_k(
        const float* __restrict__ xm, int N, uint4* __restrict__ xh,
        const int* __restrict__ src, const int* __restrict__ dst, int E, int NQ, int QPB,
        unsigned* __restrict__ gcount, unsigned* __restrict__ ebuf, int C, int nbins,
        uint2* __restrict__ ovf, unsigned* __restrict__ ocur) {
    __shared__ unsigned lcount[MAXBINS];
    __shared__ unsigned lbase[MAXBINS];
    __shared__ unsigned lcur[MAXBINS];
    __shared__ unsigned cstart[MAXBINS];
    __shared__ unsigned wsum[8];
    __shared__ unsigned spk[SC2_CHQ * 4];          // 12.5 KB payload
    __shared__ unsigned short sbin[SC2_CHQ * 4];   // 6.25 KB bin ids
    int tid = threadIdx.x;
    for (int i = tid; i < MAXBINS; i += SC2_THREADS) { lcount[i] = 0u; lcur[i] = 0u; }

    int gid = blockIdx.x * SC2_THREADS + tid;
    int gstride = gridDim.x * SC2_THREADS;
    for (int n = gid; n < N; n += gstride) {
        const float2* r = (const float2*)(xm + (size_t)n * TDIM);
        float2 a = r[0], b = r[1], c = r[2];
        __half2 h0 = __floats2half2_rn(a.x, a.y);
        __half2 h1 = __floats2half2_rn(b.x, b.y);
        __half2 h2 = __floats2half2_rn(c.x, c.y);
        uint4 o;
        o.x = *(unsigned*)&h0; o.y = *(unsigned*)&h1; o.z = *(unsigned*)&h2; o.w = 0u;
        xh[n] = o;
    }
    if (blockIdx.x == 0) {
        for (int e = NQ * 4 + tid; e < E; e += SC2_THREADS) {
            unsigned oc = atomicAdd(ocur, 1u);
            if (oc < OVF_ENT) ovf[oc] = make_uint2((unsigned)src[e], (unsigned)dst[e]);
        }
    }
    __syncthreads();

    int qb = blockIdx.x * QPB;
    int qend = qb + QPB; if (qend > NQ) qend = NQ;
    const int4* s4p = (const int4*)src;
    const int4* d4p = (const int4*)dst;

    // phase 0: block-wide dst histogram
    for (int q = qb + tid; q < qend; q += SC2_THREADS) {
        int4 dv = d4p[q];
        atomicAdd(&lcount[((unsigned)dv.x) >> BINSHIFT], 1u);
        atomicAdd(&lcount[((unsigned)dv.y) >> BINSHIFT], 1u);
        atomicAdd(&lcount[((unsigned)dv.z) >> BINSHIFT], 1u);
        atomicAdd(&lcount[((unsigned)dv.w) >> BINSHIFT], 1u);
    }
    __syncthreads();
    // phase 0b: reserve the block's whole per-bin space once (long runs)
    for (int i = tid; i < nbins; i += SC2_THREADS) {
        unsigned c = lcount[i];
        if (c) lbase[i] = atomicAdd(&gcount[i], c);
    }
    __syncthreads();

    for (int ch = 0; ch < SC2_CHUNKS; ch++) {
        int cb = qb + ch * SC2_CHQ;
        if (cb >= qend) break;
        int ce = cb + SC2_CHQ; if (ce > qend) ce = qend;
        for (int i = tid; i < MAXBINS; i += SC2_THREADS) lcount[i] = 0u;
        __syncthreads();

        unsigned pk[SC2_TQ * 4];
        unsigned wr[SC2_TQ * 4];
#pragma unroll
        for (int i = 0; i < SC2_TQ; i++) {
            int q = cb + tid + i * SC2_THREADS;
            if (q < ce) {
                int4 sv = s4p[q];
                int4 dv = d4p[q];
                {
                    unsigned du = (unsigned)dv.x, b = du >> BINSHIFT;
                    pk[i*4+0] = ((du & (BINSZ-1)) << 18) | (unsigned)sv.x;
                    wr[i*4+0] = (b << 18) | atomicAdd(&lcount[b], 1u);
                }
                {
                    unsigned du = (unsigned)dv.y, b = du >> BINSHIFT;
                    pk[i*4+1] = ((du & (BINSZ-1)) << 18) | (unsigned)sv.y;
                    wr[i*4+1] = (b << 18) | atomicAdd(&lcount[b], 1u);
                }
                {
                    unsigned du = (unsigned)dv.z, b = du >> BINSHIFT;
                    pk[i*4+2] = ((du & (BINSZ-1)) << 18) | (unsigned)sv.z;
                    wr[i*4+2] = (b << 18) | atomicAdd(&lcount[b], 1u);
                }
                {
                    unsigned du = (unsigned)dv.w, b = du >> BINSHIFT;
                    pk[i*4+3] = ((du & (BINSZ-1)) << 18) | (unsigned)sv.w;
                    wr[i*4+3] = (b << 18) | atomicAdd(&lcount[b], 1u);
                }
            } else {
                pk[i*4+0] = 0xFFFFFFFFu; pk[i*4+1] = 0xFFFFFFFFu;
                pk[i*4+2] = 0xFFFFFFFFu; pk[i*4+3] = 0xFFFFFFFFu;
            }
        }
        __syncthreads();

        // chunk-local exclusive scan of lcount (2 bins/thread, wave-shfl)
        unsigned a0 = lcount[2*tid], a1 = lcount[2*tid+1];
        {
            unsigned s = a0 + a1;
            int lane = tid & 63;
#pragma unroll
            for (int off = 1; off < 64; off <<= 1) {
                unsigned t = (unsigned)__shfl_up((int)s, off, 64);
                if (lane >= off) s += t;
            }
            if (lane == 63) wsum[tid >> 6] = s;
            __syncthreads();
            unsigned add = 0; int w = tid >> 6;
#pragma unroll
            for (int ww = 0; ww < 7; ww++) if (ww < w) add += wsum[ww];
            unsigned excl = s + add - (a0 + a1);
            cstart[2*tid] = excl;
            cstart[2*tid+1] = excl + a0;
        }
        __syncthreads();

        // scatter into sorted LDS buffers (payload + bin id)
#pragma unroll
        for (int k = 0; k < SC2_TQ * 4; k++) {
            unsigned p = pk[k];
            if (p != 0xFFFFFFFFu) {
                unsigned b = wr[k] >> 18;
                unsigned r = wr[k] & 0x3FFFFu;
                unsigned li = cstart[b] + r;
                spk[li] = p;
                sbin[li] = (unsigned short)b;
            }
        }
        __syncthreads();

        // coalesced write-out; position recomputed from LDS state; overflow here
        unsigned T = cstart[MAXBINS-1] + lcount[MAXBINS-1];
        for (unsigned j = tid; j < T; j += SC2_THREADS) {
            unsigned p = spk[j];
            unsigned b = (unsigned)sbin[j];
            unsigned pos = lbase[b] + lcur[b] + (j - cstart[b]);
            if (pos < (unsigned)C) {
                ebuf[b * (unsigned)C + pos] = p;
            } else {
                unsigned oc = atomicAdd(ocur, 1u);
                if (oc < OVF_ENT) {
                    ovf[oc] = make_uint2(p & 0x3FFFFu,
                                         (b << BINSHIFT) | (p >> 18));
                }
            }
        }
        // advance per-bin cursors (this thread owns bins 2*tid, 2*tid+1)
        lcur[2*tid]   += a0;
        lcur[2*tid+1] += a1;
        __syncthreads();
    }
}

// v12 accumA (kept): 2 blocks/bin, disjoint half-ranges, partials to pbuf.
__global__ __launch_bounds__(512) void accum_a_k(
        const uint4* __restrict__ xh,
        const unsigned* __restrict__ ebuf, const unsigned* __restrict__ gcount, int C,
        const unsigned* __restrict__ ocur, const uint2* __restrict__ ovf,
        float* __restrict__ pbuf, int nbins) {
    __shared__ unsigned srt[SRT_HALF];
    __shared__ unsigned cnt[BINSZ];
    __shared__ unsigned cstart[BINSZ];
    __shared__ unsigned wsum[4];
    __shared__ unsigned ovl[256];
    __shared__ unsigned ovn;
    float (*part)[BINSZ][TDIM] = (float(*)[BINSZ][TDIM])srt;
    int tid = threadIdx.x;
    int bh = blockIdx.x;
    int bin = bh >> 1;
    unsigned half = (unsigned)(bh & 1);
    if (tid < BINSZ) cnt[tid] = 0u;
    if (tid == 0) ovn = 0u;
    __syncthreads();

    unsigned gc = gcount[bin];
    unsigned m = gc < (unsigned)C ? gc : (unsigned)C;
    unsigned lo = half ? (m >> 1) : 0u;
    unsigned hi = half ? m : (m >> 1);
    unsigned e0 = (unsigned)bin * (unsigned)C;

    unsigned ed_[AH_EPT];
    unsigned rk_[AH_EPT];
#pragma unroll
    for (int k = 0; k < AH_EPT; k++) {
        ed_[k] = 0xFFFFFFFFu;
        unsigned i = lo + (unsigned)tid + (unsigned)k * 512u;
        if (i < hi) {
            unsigned v = __builtin_nontemporal_load(ebuf + e0 + i);
            ed_[k] = v;
            rk_[k] = atomicAdd(&cnt[v >> 18], 1u);
        }
    }
    if (half == 0u) {
        unsigned novf = *ocur;
        if (novf > OVF_ENT) novf = OVF_ENT;
        for (unsigned i = tid; i < novf; i += 512u) {
            uint2 e = ovf[i];
            if ((e.y >> BINSHIFT) == (unsigned)bin) {
                unsigned u = atomicAdd(&ovn, 1u);
                if (u < 256u) ovl[u] = ((e.y & (BINSZ-1)) << 18) | e.x;
            }
        }
    }
    __syncthreads();

    {
        unsigned v = (tid < BINSZ) ? cnt[tid] : 0u;
        int lane = tid & 63;
#pragma unroll
        for (int off = 1; off < 64; off <<= 1) {
            unsigned t = (unsigned)__shfl_up((int)v, off, 64);
            if (lane >= off) v += t;
        }
        if (tid < BINSZ && lane == 63) wsum[tid >> 6] = v;
        __syncthreads();
        if (tid < BINSZ) {
            unsigned add = 0;
            int w = tid >> 6;
#pragma unroll
            for (int ww = 0; ww < 3; ww++) if (ww < w) add += wsum[ww];
            cstart[tid] = v + add - cnt[tid];
        }
        __syncthreads();
    }

#pragma unroll
    for (int k = 0; k < AH_EPT; k++) {
        unsigned v = ed_[k];
        if (v != 0xFFFFFFFFu) srt[cstart[v >> 18] + rk_[k]] = v & 0x3FFFFu;
    }
    __syncthreads();

    int node = tid & (BINSZ - 1);
    int role = tid >> 8;
    float s0 = 0.f, s1 = 0.f, s2 = 0.f, s3 = 0.f, s4 = 0.f, s5 = 0.f;
    {
        unsigned c = cnt[node];
        unsigned b0 = cstart[node];
        unsigned h2 = c >> 1;
        unsigned j  = role ? h2 : 0u;
        unsigned je = role ? c : h2;
        for (; j + 8 <= je; j += 8) {
            unsigned i0 = srt[b0 + j],     i1 = srt[b0 + j + 1];
            unsigned i2 = srt[b0 + j + 2], i3 = srt[b0 + j + 3];
            unsigned i4 = srt[b0 + j + 4], i5 = srt[b0 + j + 5];
            unsigned i6 = srt[b0 + j + 6], i7 = srt[b0 + j + 7];
            uint4 r0 = xh[i0], r1 = xh[i1], r2 = xh[i2], r3 = xh[i3];
            uint4 r4 = xh[i4], r5 = xh[i5], r6 = xh[i6], r7 = xh[i7];
            add_row4(r0, s0, s1, s2, s3, s4, s5);
            add_row4(r1, s0, s1, s2, s3, s4, s5);
            add_row4(r2, s0, s1, s2, s3, s4, s5);
            add_row4(r3, s0, s1, s2, s3, s4, s5);
            add_row4(r4, s0, s1, s2, s3, s4, s5);
            add_row4(r5, s0, s1, s2, s3, s4, s5);
            add_row4(r6, s0, s1, s2, s3, s4, s5);
            add_row4(r7, s0, s1, s2, s3, s4, s5);
        }
        for (; j + 2 <= je; j += 2) {
            unsigned ia = srt[b0 + j], ib = srt[b0 + j + 1];
            uint4 ra = xh[ia], rb = xh[ib];
            add_row4(ra, s0, s1, s2, s3, s4, s5);
            add_row4(rb, s0, s1, s2, s3, s4, s5);
        }
        if (j < je) {
            uint4 ra = xh[srt[b0 + j]];
            add_row4(ra, s0, s1, s2, s3, s4, s5);
        }
        if (role == 0) {
            unsigned no = ovn < 256u ? ovn : 256u;
            for (unsigned q = 0; q < no; q++) {
                unsigned o = ovl[q];
                if ((int)(o >> 18) == node) {
                    uint4 rr = xh[o & 0x3FFFFu];
                    add_row4(rr, s0, s1, s2, s3, s4, s5);
                }
            }
        }
    }
    __syncthreads();
    part[role][node][0] = s0; part[role][node][1] = s1; part[role][node][2] = s2;
    part[role][node][3] = s3; part[role][node][4] = s4; part[role][node][5] = s5;
    __syncthreads();

    float* pb = pbuf + (size_t)bh * PB_NODE;
    for (int j = tid; j < PB_NODE; j += 512) {
        int nd = j / TDIM, d = j - nd * TDIM;
        pb[j] = part[0][nd][d] + part[1][nd][d];
    }
}

// v12 accumB (kept): fully-parallel fused MLP over nodes.
__global__ __launch_bounds__(256) void accum_b_k(
        const float* __restrict__ xm, const float* __restrict__ pbuf,
        const float* __restrict__ H, const float* __restrict__ W,
        float* __restrict__ facc, int N) {
    __shared__ float sH[LDIM * TDIM * MDIM];
    __shared__ float sW[LDIM];
    __shared__ float sred[4][MDIM];
    int tid = threadIdx.x;
    for (int i = tid; i < LDIM * TDIM * MDIM; i += 256) sH[i] = H[i];
    if (tid < LDIM) sW[tid] = W[tid];
    __syncthreads();

    int n = blockIdx.x * 256 + tid;
    float fs[MDIM];
#pragma unroll
    for (int mm = 0; mm < MDIM; mm++) fs[mm] = 0.f;

    if (n < N) {
        int bin = n >> BINSHIFT;
        int node = n & (BINSZ - 1);
        const float* p0 = pbuf + (size_t)(bin * 2 + 0) * PB_NODE + node * TDIM;
        const float* p1 = pbuf + (size_t)(bin * 2 + 1) * PB_NODE + node * TDIM;
        const float2* xr = (const float2*)(xm + (size_t)n * TDIM);
        float2 x0 = xr[0], x1 = xr[1], x2 = xr[2];
        float v[TDIM];
        v[0] = x0.x + p0[0] + p1[0];
        v[1] = x0.y + p0[1] + p1[1];
        v[2] = x1.x + p0[2] + p1[2];
        v[3] = x1.y + p0[3] + p1[3];
        v[4] = x2.x + p0[4] + p1[4];
        v[5] = x2.y + p0[5] + p1[5];

#pragma unroll
        for (int l = 0; l < LDIM; l++) {
            float z[MDIM];
#pragma unroll
            for (int mm = 0; mm < MDIM; mm++) {
                float a2 = 0.f;
#pragma unroll
                for (int t = 0; t < TDIM; t++) a2 += v[t] * sH[(l * TDIM + t) * MDIM + mm];
                z[mm] = a2;
            }
            float wl = sW[l];
            float mx = -1e30f;
#pragma unroll
            for (int mm = 0; mm < MDIM; mm++) {
                float sg = wl / (1.f + __expf(-z[mm]));
                z[mm] = sg;
                mx = fmaxf(mx, sg);
            }
            float se = 0.f;
#pragma unroll
            for (int mm = 0; mm < MDIM; mm++) {
                float e = __expf(z[mm] - mx);
                z[mm] = e;
                se += e;
            }
            float inv = 1.f / se;
#pragma unroll
            for (int mm = 0; mm < MDIM; mm++) fs[mm] += z[mm] * inv;
        }
    }

#pragma unroll
    for (int mm = 0; mm < MDIM; mm++) {
        float v = fs[mm];
#pragma unroll
        for (int off = 32; off > 0; off >>= 1) v += __shfl_down(v, off, 64);
        fs[mm] = v;
    }
    int wave = tid >> 6, lane = tid & 63;
    if (lane == 0) {
#pragma unroll
        for (int mm = 0; mm < MDIM; mm++) sred[wave][mm] = fs[mm];
    }
    __syncthreads();
    if (tid < MDIM) {
        float s = 0.f;
#pragma unroll
        for (int w = 0; w < 4; w++) s += sred[w][tid];
        atomicAdd(facc + tid, s);
    }
}

// v11 accum2 (kept as fallback when pbuf doesn't fit in workspace)
__global__ __launch_bounds__(AC_BLOCK) void accum2_k(
        const float* __restrict__ xm, const uint4* __restrict__ xh,
        const unsigned* __restrict__ ebuf, const unsigned* __restrict__ gcount, int C,
        const unsigned* __restrict__ ocur, const uint2* __restrict__ ovf,
        const float* __restrict__ H, const float* __restrict__ W,
        float* __restrict__ facc, int N) {
    __shared__ unsigned srt[AC_CAP];
    __shared__ unsigned cnt[BINSZ];
    __shared__ unsigned cstart[BINSZ];
    __shared__ unsigned wsum[8];
    __shared__ unsigned ovl[256];
    __shared__ unsigned ovn;
    __shared__ float sH[LDIM * TDIM * MDIM];
    __shared__ float sW[LDIM];
    __shared__ float sred[AC_BLOCK / 64][MDIM];
    float (*part)[BINSZ][TDIM] = (float(*)[BINSZ][TDIM])srt;
    int tid = threadIdx.x;
    int bin = blockIdx.x;
    for (int i = tid; i < LDIM * TDIM * MDIM; i += AC_BLOCK) sH[i] = H[i];
    if (tid < LDIM) sW[tid] = W[tid];
    if (tid < BINSZ) cnt[tid] = 0u;
    if (tid == 0) ovn = 0u;
    __syncthreads();

    unsigned gc = gcount[bin];
    unsigned m = gc < (unsigned)C ? gc : (unsigned)C;
    unsigned e0 = (unsigned)bin * (unsigned)C;
    int nbase = bin << BINSHIFT;

    unsigned ed_[AC_EPT];
    unsigned rk_[AC_EPT];
#pragma unroll
    for (int k = 0; k < AC_EPT; k++) {
        unsigned i = (unsigned)tid + (unsigned)k * AC_BLOCK;
        if (i < m) {
            unsigned v = __builtin_nontemporal_load(ebuf + e0 + i);
            ed_[k] = v;
            rk_[k] = atomicAdd(&cnt[v >> 18], 1u);
        }
    }
    {
        unsigned novf = *ocur;
        if (novf > OVF_ENT) novf = OVF_ENT;
        for (unsigned i = tid; i < novf; i += AC_BLOCK) {
            uint2 e = ovf[i];
            if ((e.y >> BINSHIFT) == (unsigned)bin) {
                unsigned u = atomicAdd(&ovn, 1u);
                if (u < 256u) ovl[u] = ((e.y & (BINSZ-1)) << 18) | e.x;
            }
        }
    }
    __syncthreads();

    {
        unsigned v = (tid < BINSZ) ? cnt[tid] : 0u;
        int lane = tid & 63;
#pragma unroll
        for (int off = 1; off < 64; off <<= 1) {
            unsigned t = (unsigned)__shfl_up((int)v, off, 64);
            if (lane >= off) v += t;
        }
        if (tid < BINSZ && lane == 63) wsum[tid >> 6] = v;
        __syncthreads();
        if (tid < BINSZ) {
            unsigned add = 0;
            int w = tid >> 6;
#pragma unroll
            for (int ww = 0; ww < 3; ww++) if (ww < w) add += wsum[ww];
            cstart[tid] = v + add - cnt[tid];
        }
        __syncthreads();
    }

#pragma unroll
    for (int k = 0; k < AC_EPT; k++) {
        unsigned i = (unsigned)tid + (unsigned)k * AC_BLOCK;
        if (i < m) {
            unsigned v = ed_[k];
            srt[cstart[v >> 18] + rk_[k]] = v & 0x3FFFFu;
        }
    }
    __syncthreads();

    int node = tid & (BINSZ - 1);
    int role = tid >> 8;
    int n = nbase + node;
    float s0 = 0.f, s1 = 0.f, s2 = 0.f, s3 = 0.f, s4 = 0.f, s5 = 0.f;
    if (n < N) {
        unsigned c = cnt[node];
        unsigned b0 = cstart[node];
        unsigned h = c >> 1;
        unsigned j  = role ? h : 0u;
        unsigned je = role ? c : h;
        for (; j + 8 <= je; j += 8) {
            unsigned i0 = srt[b0 + j],     i1 = srt[b0 + j + 1];
            unsigned i2 = srt[b0 + j + 2], i3 = srt[b0 + j + 3];
            unsigned i4 = srt[b0 + j + 4], i5 = srt[b0 + j + 5];
            unsigned i6 = srt[b0 + j + 6], i7 = srt[b0 + j + 7];
            uint4 r0 = xh[i0], r1 = xh[i1], r2 = xh[i2], r3 = xh[i3];
            uint4 r4 = xh[i4], r5 = xh[i5], r6 = xh[i6], r7 = xh[i7];
            add_row4(r0, s0, s1, s2, s3, s4, s5);
            add_row4(r1, s0, s1, s2, s3, s4, s5);
            add_row4(r2, s0, s1, s2, s3, s4, s5);
            add_row4(r3, s0, s1, s2, s3, s4, s5);
            add_row4(r4, s0, s1, s2, s3, s4, s5);
            add_row4(r5, s0, s1, s2, s3, s4, s5);
            add_row4(r6, s0, s1, s2, s3, s4, s5);
            add_row4(r7, s0, s1, s2, s3, s4, s5);
        }
        for (; j + 2 <= je; j += 2) {
            unsigned ia = srt[b0 + j], ib = srt[b0 + j + 1];
            uint4 ra = xh[ia], rb = xh[ib];
            add_row4(ra, s0, s1, s2, s3, s4, s5);
            add_row4(rb, s0, s1, s2, s3, s4, s5);
        }
        if (j < je) {
            uint4 ra = xh[srt[b0 + j]];
            add_row4(ra, s0, s1, s2, s3, s4, s5);
        }
        if (role == 0) {
            unsigned no = ovn < 256u ? ovn : 256u;
            for (unsigned q = 0; q < no; q++) {
                unsigned o = ovl[q];
                if ((int)(o >> 18) == node) {
                    uint4 rr = xh[o & 0x3FFFFu];
                    add_row4(rr, s0, s1, s2, s3, s4, s5);
                }
            }
        }
    }
    __syncthreads();
    part[role][node][0] = s0; part[role][node][1] = s1; part[role][node][2] = s2;
    part[role][node][3] = s3; part[role][node][4] = s4; part[role][node][5] = s5;
    __syncthreads();

    float fs[MDIM];
#pragma unroll
    for (int mm = 0; mm < MDIM; mm++) fs[mm] = 0.f;

    if (n < N) {
        float v[TDIM];
        const float2* xr = (const float2*)(xm + (size_t)n * TDIM);
        float2 x0 = xr[0], x1 = xr[1], x2 = xr[2];
        v[0] = x0.x + part[0][node][0] + part[1][node][0];
        v[1] = x0.y + part[0][node][1] + part[1][node][1];
        v[2] = x1.x + part[0][node][2] + part[1][node][2];
        v[3] = x1.y + part[0][node][3] + part[1][node][3];
        v[4] = x2.x + part[0][node][4] + part[1][node][4];
        v[5] = x2.y + part[0][node][5] + part[1][node][5];

        int lb = role << 1;
#pragma unroll
        for (int li = 0; li < 2; li++) {
            int l = lb + li;
            float z[MDIM];
#pragma unroll
            for (int mm = 0; mm < MDIM; mm++) {
                float a2 = 0.f;
#pragma unroll
                for (int t = 0; t < TDIM; t++) a2 += v[t] * sH[(l * TDIM + t) * MDIM + mm];
                z[mm] = a2;
            }
            float wl = sW[l];
            float mx = -1e30f;
#pragma unroll
            for (int mm = 0; mm < MDIM; mm++) {
                float sg = wl / (1.f + __expf(-z[mm]));
                z[mm] = sg;
                mx = fmaxf(mx, sg);
            }
            float se = 0.f;
#pragma unroll
            for (int mm = 0; mm < MDIM; mm++) {
                float e = __expf(z[mm] - mx);
                z[mm] = e;
                se += e;
            }
            float inv = 1.f / se;
#pragma unroll
            for (int mm = 0; mm < MDIM; mm++) fs[mm] += z[mm] * inv;
        }
    }

#pragma unroll
    for (int mm = 0; mm < MDIM; mm++) {
        float v = fs[mm];
#pragma unroll
        for (int off = 32; off > 0; off >>= 1) v += __shfl_down(v, off, 64);
        fs[mm] = v;
    }
    int wave = tid >> 6, lane = tid & 63;
    if (lane == 0) {
#pragma unroll
        for (int mm = 0; mm < MDIM; mm++) sred[wave][mm] = fs[mm];
    }
    __syncthreads();
    if (tid < MDIM) {
        float s = 0.f;
#pragma unroll
        for (int w = 0; w < AC_BLOCK / 64; w++) s += sred[w][tid];
        atomicAdd(facc + tid, s);
    }
}

// ================= TIER 2: legacy hist/scan path =================

__global__ __launch_bounds__(256) void prep_k(const float* __restrict__ xm, int N,
                                              uint4* __restrict__ xh,
                                              const int* __restrict__ dst, int E,
                                              unsigned* __restrict__ hist, int nbins) {
    __shared__ unsigned lh[MAXBINS];
    for (int i = threadIdx.x; i < MAXBINS; i += blockDim.x) lh[i] = 0u;
    __syncthreads();
    int gid = blockIdx.x * blockDim.x + threadIdx.x;
    int gstride = gridDim.x * blockDim.x;
    for (int n = gid; n < N; n += gstride) {
        const float2* r = (const float2*)(xm + (size_t)n * TDIM);
        float2 a = r[0], b = r[1], c = r[2];
        __half2 h0 = __floats2half2_rn(a.x, a.y);
        __half2 h1 = __floats2half2_rn(b.x, b.y);
        __half2 h2 = __floats2half2_rn(c.x, c.y);
        uint4 o;
        o.x = *(unsigned*)&h0; o.y = *(unsigned*)&h1; o.z = *(unsigned*)&h2; o.w = 0u;
        xh[n] = o;
    }
    int e4 = E >> 2;
    const int4* d4p = (const int4*)dst;
    for (int i = gid; i < e4; i += gstride) {
        int4 d = d4p[i];
        atomicAdd(&lh[((unsigned)d.x) >> BINSHIFT], 1u);
        atomicAdd(&lh[((unsigned)d.y) >> BINSHIFT], 1u);
        atomicAdd(&lh[((unsigned)d.z) >> BINSHIFT], 1u);
        atomicAdd(&lh[((unsigned)d.w) >> BINSHIFT], 1u);
    }
    for (int e = (e4 << 2) + gid; e < E; e += gstride)
        atomicAdd(&lh[((unsigned)dst[e]) >> BINSHIFT], 1u);
    __syncthreads();
    for (int i = threadIdx.x; i < nbins; i += blockDim.x)
        if (lh[i]) atomicAdd(&hist[i], lh[i]);
}

__global__ __launch_bounds__(MAXBINS) void scan_k(const unsigned* __restrict__ hist,
                                                  unsigned* __restrict__ offsets,
                                                  unsigned* __restrict__ gfill, int nbins) {
    __shared__ unsigned buf[2][MAXBINS];
    int t = threadIdx.x;
    buf[0][t] = (t < nbins) ? hist[t] : 0u;
    __syncthreads();
    int cur = 0;
    for (int off = 1; off < MAXBINS; off <<= 1) {
        unsigned v = buf[cur][t];
        if (t >= off) v += buf[cur][t - off];
        buf[cur ^ 1][t] = v;
        __syncthreads();
        cur ^= 1;
    }
    if (t < nbins) {
        unsigned ex = t ? buf[cur][t - 1] : 0u;
        offsets[t] = ex;
        gfill[t] = ex;
    }
    if (t == 0) offsets[nbins] = buf[cur][nbins - 1];
}

__global__ __launch_bounds__(SC_BLOCK) void scatter_k(const int* __restrict__ src,
                                                      const int* __restrict__ dst, int E,
                                                      unsigned* __restrict__ gfill,
                                                      unsigned* __restrict__ ebuf, int nbins) {
    __shared__ unsigned lcount[MAXBINS];
    __shared__ unsigned lbase[MAXBINS];
    for (int i = threadIdx.x; i < MAXBINS; i += SC_BLOCK) lcount[i] = 0u;
    __syncthreads();
    int base = blockIdx.x * SC_EPB + threadIdx.x * SC_EPT;
    int s[SC_EPT], d[SC_EPT];
    unsigned rk[SC_EPT];
#pragma unroll
    for (int q = 0; q < SC_EPT / 4; q++) {
        int e = base + q * 4;
        if (e + 3 < E) {
            int4 s4 = *(const int4*)(src + e);
            int4 d4 = *(const int4*)(dst + e);
            s[q*4+0] = s4.x; s[q*4+1] = s4.y; s[q*4+2] = s4.z; s[q*4+3] = s4.w;
            d[q*4+0] = d4.x; d[q*4+1] = d4.y; d[q*4+2] = d4.z; d[q*4+3] = d4.w;
        } else {
#pragma unroll
            for (int k = 0; k < 4; k++) {
                int ee = e + k;
                s[q*4+k] = (ee < E) ? src[ee] : -1;
                d[q*4+k] = (ee < E) ? dst[ee] : 0;
            }
        }
    }
#pragma unroll
    for (int k = 0; k < SC_EPT; k++)
        if (s[k] >= 0) rk[k] = atomicAdd(&lcount[((unsigned)d[k]) >> BINSHIFT], 1u);
    __syncthreads();
    for (int i = threadIdx.x; i < nbins; i += SC_BLOCK) {
        unsigned c = lcount[i];
        if (c) lbase[i] = atomicAdd(&gfill[i], c);
    }
    __syncthreads();
#pragma unroll
    for (int k = 0; k < SC_EPT; k++) {
        if (s[k] >= 0) {
            unsigned du = (unsigned)d[k];
            unsigned b = du >> BINSHIFT;
            unsigned pack = ((du & (BINSZ - 1)) << 18) | (unsigned)s[k];
            ebuf[lbase[b] + rk[k]] = pack;
        }
    }
}

__global__ __launch_bounds__(AC_BLOCK) void accum_node_k(
        const float* __restrict__ xm, const uint4* __restrict__ xh,
        const unsigned* __restrict__ ebuf, const unsigned* __restrict__ offsets,
        const float* __restrict__ H, const float* __restrict__ W,
        float* __restrict__ facc, int N) {
    __shared__ unsigned srt[AC_CAP];
    __shared__ unsigned cnt[BINSZ];
    __shared__ unsigned tmp[BINSZ];
    __shared__ unsigned cstart[BINSZ];
    __shared__ float sH[LDIM * TDIM * MDIM];
    __shared__ float sW[LDIM];
    __shared__ float sred[AC_BLOCK / 64][MDIM];
    int tid = threadIdx.x;
    int bin = blockIdx.x;
    for (int i = tid; i < LDIM * TDIM * MDIM; i += AC_BLOCK) sH[i] = H[i];
    if (tid < LDIM) sW[tid] = W[tid];
    if (tid < BINSZ) cnt[tid] = 0u;
    __syncthreads();

    unsigned e0 = offsets[bin], e1 = offsets[bin + 1];
    unsigned total = e1 - e0;
    unsigned m = total < AC_CAP ? total : AC_CAP;
    int nbase = bin << BINSHIFT;

    unsigned ed_[AC_EPT];
    unsigned rk_[AC_EPT];
#pragma unroll
    for (int k = 0; k < AC_EPT; k++) {
        unsigned idx = e0 + (unsigned)tid + (unsigned)k * AC_BLOCK;
        if (idx < e0 + m) {
            unsigned v = ebuf[idx];
            ed_[k] = v;
            rk_[k] = atomicAdd(&cnt[v >> 18], 1u);
        }
    }
    __syncthreads();

    if (tid < BINSZ) tmp[tid] = cnt[tid];
    __syncthreads();
    for (int off = 1; off < BINSZ; off <<= 1) {
        unsigned v = 0;
        if (tid < BINSZ) { v = tmp[tid]; if (tid >= off) v += tmp[tid - off]; }
        __syncthreads();
        if (tid < BINSZ) tmp[tid] = v;
        __syncthreads();
    }
    if (tid < BINSZ) cstart[tid] = tmp[tid] - cnt[tid];
    __syncthreads();

#pragma unroll
    for (int k = 0; k < AC_EPT; k++) {
        unsigned idx = e0 + (unsigned)tid + (unsigned)k * AC_BLOCK;
        if (idx < e0 + m) {
            unsigned v = ed_[k];
            srt[cstart[v >> 18] + rk_[k]] = v & 0x3FFFFu;
        }
    }
    __syncthreads();

    float fs[MDIM];
#pragma unroll
    for (int mm = 0; mm < MDIM; mm++) fs[mm] = 0.f;

    int n = nbase + tid;
    if (tid < BINSZ && n < N) {
        float s0 = 0.f, s1 = 0.f, s2 = 0.f, s3 = 0.f, s4 = 0.f, s5 = 0.f;
        unsigned c = cnt[tid];
        unsigned b0 = cstart[tid];
        unsigned j = 0;
        for (; j + 2 <= c; j += 2) {
            unsigned sa = srt[b0 + j], sb = srt[b0 + j + 1];
            uint4 ra = xh[sa];
            uint4 rb = xh[sb];
            add_row4(ra, s0, s1, s2, s3, s4, s5);
            add_row4(rb, s0, s1, s2, s3, s4, s5);
        }
        if (j < c) {
            uint4 ra = xh[srt[b0 + j]];
            add_row4(ra, s0, s1, s2, s3, s4, s5);
        }
        for (unsigned idx = e0 + m; idx < e1; idx++) {
            unsigned v = ebuf[idx];
            if ((int)(v >> 18) == tid) {
                uint4 ra = xh[v & 0x3FFFFu];
                add_row4(ra, s0, s1, s2, s3, s4, s5);
            }
        }

        float v[TDIM];
        const float2* xr = (const float2*)(xm + (size_t)n * TDIM);
        float2 x0 = xr[0], x1 = xr[1], x2 = xr[2];
        v[0] = x0.x + s0; v[1] = x0.y + s1;
        v[2] = x1.x + s2; v[3] = x1.y + s3;
        v[4] = x2.x + s4; v[5] = x2.y + s5;

#pragma unroll
        for (int l = 0; l < LDIM; l++) {
            float z[MDIM];
#pragma unroll
            for (int mm = 0; mm < MDIM; mm++) {
                float a2 = 0.f;
#pragma unroll
                for (int t = 0; t < TDIM; t++) a2 += v[t] * sH[(l * TDIM + t) * MDIM + mm];
                z[mm] = a2;
            }
            float wl = sW[l];
            float mx = -1e30f;
#pragma unroll
            for (int mm = 0; mm < MDIM; mm++) {
                float sg = wl / (1.f + __expf(-z[mm]));
                z[mm] = sg;
                mx = fmaxf(mx, sg);
            }
            float se = 0.f;
#pragma unroll
            for (int mm = 0; mm < MDIM; mm++) {
                float e = __expf(z[mm] - mx);
                z[mm] = e;
                se += e;
            }
            float inv = 1.f / se;
#pragma unroll
            for (int mm = 0; mm < MDIM; mm++) fs[mm] += z[mm] * inv;
        }
    }

#pragma unroll
    for (int mm = 0; mm < MDIM; mm++) {
        float v = fs[mm];
#pragma unroll
        for (int off = 32; off > 0; off >>= 1) v += __shfl_down(v, off, 64);
        fs[mm] = v;
    }
    int wave = tid >> 6, lane = tid & 63;
    if (lane == 0) {
#pragma unroll
        for (int mm = 0; mm < MDIM; mm++) sred[wave][mm] = fs[mm];
    }
    __syncthreads();
    if (tid < MDIM) {
        float s = 0.f;
#pragma unroll
        for (int w = 0; w < AC_BLOCK / 64; w++) s += sred[w][tid];
        atomicAdd(facc + tid, s);
    }
}

// ---------------- final tiny perceptron ----------------
__global__ void finalize_k(const float* __restrict__ facc,
                           const float* __restrict__ xg,
                           const float* __restrict__ gW,
                           const float* __restrict__ gb,
                           const float* __restrict__ mW,
                           const float* __restrict__ mb,
                           float* __restrict__ out) {
    if (threadIdx.x == 0 && blockIdx.x == 0) {
        float merged[MDIM + GLOD];
#pragma unroll
        for (int m = 0; m < MDIM; m++) merged[m] = facc[m];
        for (int j = 0; j < GLOD; j++) {
            float a = gb[j];
            for (int i = 0; i < GIND; i++) a += xg[i] * gW[j * GIND + i];
            merged[MDIM + j] = 1.f / (1.f + __expf(-a));
        }
        float lg[3];
        float mx = -1e30f;
        for (int k = 0; k < 3; k++) {
            float a = mb[k];
            for (int j = 0; j < MDIM + GLOD; j++) a += merged[j] * mW[k * (MDIM + GLOD) + j];
            lg[k] = a;
            mx = fmaxf(mx, a);
        }
        float se = 0.f;
        for (int k = 0; k < 3; k++) { lg[k] = __expf(lg[k] - mx); se += lg[k]; }
        float inv = 1.f / se;
        for (int k = 0; k < 3; k++) out[k] = lg[k] * inv;
    }
}

// ---------------- TIER 3 fallback: global-atomic path ----------------
__global__ void fb_zero_k(float* __restrict__ ws, int n) {
    int i = blockIdx.x * blockDim.x + threadIdx.x;
    if (i < n) ws[i] = 0.f;
}

__global__ void fb_edge_scatter_k(const float* __restrict__ xm,
                                  const int* __restrict__ src,
                                  const int* __restrict__ dst,
                                  float* __restrict__ neigh, int E) {
    int e = blockIdx.x * blockDim.x + threadIdx.x;
    if (e >= E) return;
    int s = src[e], d = dst[e];
    const float2* r = (const float2*)(xm + (size_t)s * TDIM);
    float2 a = r[0], b = r[1], c = r[2];
    float* o = neigh + (size_t)d * TDIM;
    atomicAdd(o + 0, a.x); atomicAdd(o + 1, a.y);
    atomicAdd(o + 2, b.x); atomicAdd(o + 3, b.y);
    atomicAdd(o + 4, c.x); atomicAdd(o + 5, c.y);
}

__global__ __launch_bounds__(256) void fb_node_k(
        const float* __restrict__ xm, const float* __restrict__ neigh,
        const float* __restrict__ H, const float* __restrict__ W,
        float* __restrict__ facc, int N) {
    __shared__ float sH[LDIM * TDIM * MDIM];
    __shared__ float sW[LDIM];
    __shared__ float sred[4][MDIM];
    int tid = threadIdx.x;
    for (int i = tid; i < LDIM * TDIM * MDIM; i += blockDim.x) sH[i] = H[i];
    if (tid < LDIM) sW[tid] = W[tid];
    __syncthreads();
    float fs[MDIM];
#pragma unroll
    for (int m = 0; m < MDIM; m++) fs[m] = 0.f;
    for (int n = blockIdx.x * blockDim.x + tid; n < N; n += gridDim.x * blockDim.x) {
        float v[TDIM];
        const float2* xr = (const float2*)(xm + (size_t)n * TDIM);
        const float2* nr = (const float2*)(neigh + (size_t)n * TDIM);
#pragma unroll
        for (int t2 = 0; t2 < 3; t2++) {
            float2 a = xr[t2], b = nr[t2];
            v[2 * t2 + 0] = a.x + b.x;
            v[2 * t2 + 1] = a.y + b.y;
        }
#pragma unroll
        for (int l = 0; l < LDIM; l++) {
            float z[MDIM];
#pragma unroll
            for (int m = 0; m < MDIM; m++) {
                float a2 = 0.f;
#pragma unroll
                for (int t = 0; t < TDIM; t++) a2 += v[t] * sH[(l * TDIM + t) * MDIM + m];
                z[m] = a2;
            }
            float wl = sW[l], mx = -1e30f;
#pragma unroll
            for (int m = 0; m < MDIM; m++) { float sg = wl / (1.f + __expf(-z[m])); z[m] = sg; mx = fmaxf(mx, sg); }
            float se = 0.f;
#pragma unroll
            for (int m = 0; m < MDIM; m++) { float e = __expf(z[m] - mx); z[m] = e; se += e; }
            float inv = 1.f / se;
#pragma unroll
            for (int m = 0; m < MDIM; m++) fs[m] += z[m] * inv;
        }
    }
#pragma unroll
    for (int m = 0; m < MDIM; m++) {
        float v = fs[m];
#pragma unroll
        for (int off = 32; off > 0; off >>= 1) v += __shfl_down(v, off, 64);
        fs[m] = v;
    }
    int wave = tid >> 6, lane = tid & 63;
    if (lane == 0) {
#pragma unroll
        for (int m = 0; m < MDIM; m++) sred[wave][m] = fs[m];
    }
    __syncthreads();
    if (tid < MDIM) {
        float s = sred[0][tid] + sred[1][tid] + sred[2][tid] + sred[3][tid];
        atomicAdd(facc + tid, s);
    }
}

extern "C" void kernel_launch(void* const* d_in, const int* in_sizes, int n_in,
                              void* d_out, int out_size, void* d_ws, size_t ws_size,
                              hipStream_t stream) {
    const float* xm  = (const float*)d_in[0];
    const float* xg  = (const float*)d_in[1];
    const int*   src = (const int*)d_in[2];
    const int*   dst = (const int*)d_in[3];
    const float* H   = (const float*)d_in[4];
    const float* W   = (const float*)d_in[5];
    const float* gW  = (const float*)d_in[6];
    const float* gb  = (const float*)d_in[7];
    const float* mW  = (const float*)d_in[8];
    const float* mb  = (const float*)d_in[9];
    float* out = (float*)d_out;

    int N = in_sizes[0] / TDIM;
    int E = in_sizes[2];
    int nbins = (N + BINSZ - 1) >> BINSHIFT;
    size_t ws_words = ws_size / 4;
    size_t xh_words = (size_t)N * 4;
    size_t pbuf_words = (size_t)nbins * 2 * PB_NODE;

    double mu = (double)E / nbins;
    long Cmin = (long)(mu + 4.0 * sqrt(mu) + 32.0);
    int NQ = E >> 2;
    int QPB = (NQ + SC2_BLOCKS - 1) / SC2_BLOCKS;
    bool qpb_ok = QPB <= SC2_CHUNKS * SC2_CHQ;

    // ---- tier 1a: split accum (needs pbuf) ----
    long fixed_s = (long)(xh_words + META2 + (size_t)OVF_ENT * 2 + pbuf_words);
    long avail_s = (long)ws_words - fixed_s;
    long Cs = avail_s > 0 ? (avail_s / nbins) & ~3L : 0;
    if (Cs > AC_CAP) Cs = AC_CAP;
    bool ok1s = (Cs >= Cmin) && nbins <= MAXBINS && N <= (1 << 18) && qpb_ok;

    // ---- tier 1b: v11 single-kernel accum ----
    long fixed = (long)(xh_words + META2 + (size_t)OVF_ENT * 2);
    long avail = (long)ws_words - fixed;
    long C = avail > 0 ? (avail / nbins) & ~3L : 0;
    if (C > AC_CAP) C = AC_CAP;
    bool ok1 = (C >= Cmin) && nbins <= MAXBINS && N <= (1 << 18) && qpb_ok;

    // ---- tier 2: legacy hist/scan ----
    size_t meta_words2 = MAXBINS + (MAXBINS + 1) + MAXBINS + 16;
    size_t need2 = (xh_words + (size_t)E + meta_words2) * 4;
    bool ok2 = ws_size >= need2 && nbins <= MAXBINS && N <= (1 << 18);

    if (ok1s) {
        uint4*    xh     = (uint4*)d_ws;
        unsigned* ebuf   = (unsigned*)d_ws + xh_words;
        unsigned* gcount = ebuf + (size_t)nbins * Cs;
        unsigned* ocur   = gcount + MAXBINS;
        float*    facc   = (float*)(ocur + 16);
        uint2*    ovf    = (uint2*)(gcount + META2);
        float*    pbuf   = (float*)(gcount + META2 + (size_t)OVF_ENT * 2);

        zero32_k<<<(META2 + 255) / 256, 256, 0, stream>>>(gcount, META2);
        scat2_k<<<SC2_BLOCKS, SC2_THREADS, 0, stream>>>(xm, N, xh, src, dst, E, NQ, QPB,
                                                        gcount, ebuf, (int)Cs, nbins, ovf, ocur);
        accum_a_k<<<nbins * 2, 512, 0, stream>>>(xh, ebuf, gcount, (int)Cs, ocur, ovf,
                                                 pbuf, nbins);
        accum_b_k<<<(N + 255) / 256, 256, 0, stream>>>(xm, pbuf, H, W, facc, N);
        finalize_k<<<1, 64, 0, stream>>>(facc, xg, gW, gb, mW, mb, out);
    } else if (ok1) {
        uint4*    xh     = (uint4*)d_ws;
        unsigned* ebuf   = (unsigned*)d_ws + xh_words;
        unsigned* gcount = ebuf + (size_t)nbins * C;
        unsigned* ocur   = gcount + MAXBINS;
        float*    facc   = (float*)(ocur + 16);
        uint2*    ovf    = (uint2*)(gcount + META2);

        zero32_k<<<(META2 + 255) / 256, 256, 0, stream>>>(gcount, META2);
        scat2_k<<<SC2_BLOCKS, SC2_THREADS, 0, stream>>>(xm, N, xh, src, dst, E, NQ, QPB,
                                                        gcount, ebuf, (int)C, nbins, ovf, ocur);
        accum2_k<<<nbins, AC_BLOCK, 0, stream>>>(xm, xh, ebuf, gcount, (int)C, ocur, ovf,
                                                 H, W, facc, N);
        finalize_k<<<1, 64, 0, stream>>>(facc, xg, gW, gb, mW, mb, out);
    } else if (ok2) {
        uint4*    xh      = (uint4*)d_ws;
        unsigned* ebuf    = (unsigned*)d_ws + xh_words;
        unsigned* hist    = ebuf + (size_t)E;
        unsigned* offsets = hist + MAXBINS;
        unsigned* gfill   = offsets + MAXBINS + 1;
        float*    facc    = (float*)(gfill + MAXBINS);

        zero32_k<<<(int)((meta_words2 + 255) / 256), 256, 0, stream>>>(hist, (int)meta_words2);
        prep_k<<<1024, 256, 0, stream>>>(xm, N, xh, dst, E, hist, nbins);
        scan_k<<<1, MAXBINS, 0, stream>>>(hist, offsets, gfill, nbins);
        scatter_k<<<(E + SC_EPB - 1) / SC_EPB, SC_BLOCK, 0, stream>>>(src, dst, E, gfill, ebuf, nbins);
        accum_node_k<<<nbins, AC_BLOCK, 0, stream>>>(xm, xh, ebuf, offsets, H, W, facc, N);
        finalize_k<<<1, 64, 0, stream>>>(facc, xg, gW, gb, mW, mb, out);
    } else {
        float* neigh = (float*)d_ws;
        float* facc  = neigh + (size_t)N * TDIM;
        int zn = N * TDIM + 16;
        fb_zero_k<<<(zn + 255) / 256, 256, 0, stream>>>(neigh, zn);
        fb_edge_scatter_k<<<(E + 255) / 256, 256, 0, stream>>>(xm, src, dst, neigh, E);
        fb_node_k<<<256, 256, 0, stream>>>(xm, neigh, H, W, facc, N);
        finalize_k<<<1, 64, 0, stream>>>(facc, xg, gW, gb, mW, mb, out);
    }
}

// Round 15
// 115.953 us; speedup vs baseline: 1.1017x; 1.1017x over previous
//
#include <hip/hip_runtime.h>
#include <hip/hip_fp16.h>
#include <math.h>

#define TDIM 6
#define MDIM 10
#define LDIM 4
#define GIND 14
#define GLOD 10

#define BINSHIFT 8
#define BINSZ 256            // nodes per bin
#define MAXBINS 1024         // supports N up to 262144 (pack limit: src < 2^18)

// ---- fixed-capacity scatter path ----
// v15: merged hist+rank. r14 lesson: per-block fixed bin-array work scales
// with grid (1024 blocks regressed). r11-13's hist pass duplicated the rank
// pass (2x E LDS-atomics + 8.5MB dst re-read) just to reserve space early.
// Now: rank ALL edges first (cumulative lcount, ranks in regs), snapshot at
// chunk boundaries, reserve once, then per-chunk LDS sort + coalesced write
// (global pos = lbase[b] + cumulative rank). 768 blocks x ~45KB LDS = 3/CU.
#define SC2_BLOCKS 768
#define SC2_THREADS 512
#define SC2_KQ 5             // reg-held quads per thread (QPB <= 2560 -> E <= 7.86M)
#define SC2_CHQ 1024         // quads per staging chunk (= 2 rank iterations)
#define SC2_NCH 3            // ceil(SC2_KQ / 2)
#define OVF_ENT 16384
#define META2 2048           // gcount[1024] + ocur + facc + pad

// ---- accum params ----
#define SC_BLOCK 512
#define SC_EPT 32
#define SC_EPB (SC_BLOCK * SC_EPT)
#define AC_BLOCK 512
#define AC_CAP 8704          // mean 8192 + 5.7 sigma; overflow handled via ovf path
#define AC_EPT 17            // AC_CAP / AC_BLOCK

// ---- split-accum params (v12 winner) ----
#define SRT_HALF 4352        // ceil(AC_CAP/2); 17.4 KB LDS
#define AH_EPT 9             // ceil(SRT_HALF / 512)
#define PB_NODE (BINSZ * TDIM)   // 1536 floats per (bin,half)

// ---------------- small utility ----------------
__global__ void zero32_k(unsigned* __restrict__ p, int n) {
    int i = blockIdx.x * blockDim.x + threadIdx.x;
    if (i < n) p[i] = 0u;
}

__device__ __forceinline__ void add_row4(uint4 r, float& s0, float& s1, float& s2,
                                         float& s3, float& s4, float& s5) {
    float2 a0 = __half22float2(*(__half2*)&r.x);
    float2 a1 = __half22float2(*(__half2*)&r.y);
    float2 a2 = __half22float2(*(__half2*)&r.z);
    s0 += a0.x; s1 += a0.y; s2 += a1.x; s3 += a1.y; s4 += a2.x; s5 += a2.y;
}

// ================= TIER 1: fixed-capacity bins =================

__global__ __launch_bounds__(SC2_THREADS) void scat2_k(
        const float* __restrict__ xm, int N, uint4* __restrict__ xh,
        const int* __restrict__ src, const int* __restrict__ dst, int E, int NQ, int QPB,
        unsigned* __restrict__ gcount, unsigned* __restrict__ ebuf, int C, int nbins,
        uint2* __restrict__ ovf, unsigned* __restrict__ ocur) {
    __shared__ unsigned lcount[MAXBINS];           // cumulative block ranks
    __shared__ unsigned lbase[MAXBINS];            // block's reserved base per bin
    __shared__ unsigned snap[SC2_NCH - 1][MAXBINS];// lcount at chunk boundaries
    __shared__ unsigned cstart[MAXBINS];           // chunk-local exclusive scan
    __shared__ unsigned wsum[8];
    __shared__ unsigned spk[SC2_CHQ * 4];          // 16 KB payload
    __shared__ unsigned short sbin[SC2_CHQ * 4];   // 8 KB bin ids
    int tid = threadIdx.x;
    for (int i = tid; i < MAXBINS; i += SC2_THREADS) lcount[i] = 0u;

    // build padded fp16 gather table (16 B/row), overlapped
    int gid = blockIdx.x * SC2_THREADS + tid;
    int gstride = gridDim.x * SC2_THREADS;
    for (int n = gid; n < N; n += gstride) {
        const float2* r = (const float2*)(xm + (size_t)n * TDIM);
        float2 a = r[0], b = r[1], c = r[2];
        __half2 h0 = __floats2half2_rn(a.x, a.y);
        __half2 h1 = __floats2half2_rn(b.x, b.y);
        __half2 h2 = __floats2half2_rn(c.x, c.y);
        uint4 o;
        o.x = *(unsigned*)&h0; o.y = *(unsigned*)&h1; o.z = *(unsigned*)&h2; o.w = 0u;
        xh[n] = o;
    }
    if (blockIdx.x == 0) {
        for (int e = NQ * 4 + tid; e < E; e += SC2_THREADS) {
            unsigned oc = atomicAdd(ocur, 1u);
            if (oc < OVF_ENT) ovf[oc] = make_uint2((unsigned)src[e], (unsigned)dst[e]);
        }
    }
    __syncthreads();

    int qb = blockIdx.x * QPB;
    int qend = qb + QPB; if (qend > NQ) qend = NQ;
    const int4* s4p = (const int4*)src;
    const int4* d4p = (const int4*)dst;

    unsigned pk[SC2_KQ * 4];
    unsigned wr[SC2_KQ * 4];   // (bin<<18) | cumulative block rank

    // phase A: rank ALL edges (cumulative lcount), snapshot at chunk boundaries
#pragma unroll
    for (int i = 0; i < SC2_KQ; i++) {
        int q = qb + tid + i * SC2_THREADS;
        if (q < qend) {
            int4 sv = s4p[q];
            int4 dv = d4p[q];
            {
                unsigned du = (unsigned)dv.x, b = du >> BINSHIFT;
                pk[i*4+0] = ((du & (BINSZ-1)) << 18) | (unsigned)sv.x;
                wr[i*4+0] = (b << 18) | atomicAdd(&lcount[b], 1u);
            }
            {
                unsigned du = (unsigned)dv.y, b = du >> BINSHIFT;
                pk[i*4+1] = ((du & (BINSZ-1)) << 18) | (unsigned)sv.y;
                wr[i*4+1] = (b << 18) | atomicAdd(&lcount[b], 1u);
            }
            {
                unsigned du = (unsigned)dv.z, b = du >> BINSHIFT;
                pk[i*4+2] = ((du & (BINSZ-1)) << 18) | (unsigned)sv.z;
                wr[i*4+2] = (b << 18) | atomicAdd(&lcount[b], 1u);
            }
            {
                unsigned du = (unsigned)dv.w, b = du >> BINSHIFT;
                pk[i*4+3] = ((du & (BINSZ-1)) << 18) | (unsigned)sv.w;
                wr[i*4+3] = (b << 18) | atomicAdd(&lcount[b], 1u);
            }
        } else {
            pk[i*4+0] = 0xFFFFFFFFu; pk[i*4+1] = 0xFFFFFFFFu;
            pk[i*4+2] = 0xFFFFFFFFu; pk[i*4+3] = 0xFFFFFFFFu;
        }
        // snapshot after iterations 1 and 3 (chunk = 2 iterations = 1024 quads)
        if (i == 1 || i == 3) {
            __syncthreads();
            for (int b2 = tid; b2 < MAXBINS; b2 += SC2_THREADS)
                snap[i >> 1][b2] = lcount[b2];
            __syncthreads();
        }
    }
    __syncthreads();

    // phase B: reserve the block's whole per-bin space ONCE
    for (int i = tid; i < nbins; i += SC2_THREADS) {
        unsigned c = lcount[i];
        if (c) lbase[i] = atomicAdd(&gcount[i], c);
    }
    __syncthreads();

    // phase C: per chunk — scan chunk counts, LDS sort, coalesced write
#pragma unroll
    for (int ch = 0; ch < SC2_NCH; ch++) {
        // chunk counts = end - prev
        unsigned p0 = (ch == 0) ? 0u : snap[ch-1][2*tid];
        unsigned p1 = (ch == 0) ? 0u : snap[ch-1][2*tid+1];
        unsigned e0v = (ch == SC2_NCH-1) ? lcount[2*tid]   : snap[ch][2*tid];
        unsigned e1v = (ch == SC2_NCH-1) ? lcount[2*tid+1] : snap[ch][2*tid+1];
        unsigned a0 = e0v - p0, a1 = e1v - p1;
        {
            unsigned s = a0 + a1;
            int lane = tid & 63;
#pragma unroll
            for (int off = 1; off < 64; off <<= 1) {
                unsigned t = (unsigned)__shfl_up((int)s, off, 64);
                if (lane >= off) s += t;
            }
            if (lane == 63) wsum[tid >> 6] = s;
            __syncthreads();
            unsigned add = 0; int w = tid >> 6;
#pragma unroll
            for (int ww = 0; ww < 7; ww++) if (ww < w) add += wsum[ww];
            unsigned excl = s + add - (a0 + a1);
            cstart[2*tid] = excl;
            cstart[2*tid+1] = excl + a0;
        }
        __syncthreads();

        // scatter this chunk's register entries into staging (compile-time idx)
#pragma unroll
        for (int i = ch * 2; i < ((ch * 2 + 2 < SC2_KQ) ? ch * 2 + 2 : SC2_KQ); i++) {
#pragma unroll
            for (int kk = 0; kk < 4; kk++) {
                unsigned p = pk[i*4 + kk];
                if (p != 0xFFFFFFFFu) {
                    unsigned b = wr[i*4 + kk] >> 18;
                    unsigned prevb = (ch == 0) ? 0u : snap[ch-1][b];
                    unsigned local = (wr[i*4 + kk] & 0x3FFFFu) - prevb;
                    unsigned li = cstart[b] + local;
                    spk[li] = p;
                    sbin[li] = (unsigned short)b;
                }
            }
        }
        __syncthreads();

        // coalesced write-out; pos = lbase + prev + chunk-local rank
        unsigned lastp = (ch == 0) ? 0u : snap[ch-1][MAXBINS-1];
        unsigned laste = (ch == SC2_NCH-1) ? lcount[MAXBINS-1] : snap[ch][MAXBINS-1];
        unsigned T = cstart[MAXBINS-1] + (laste - lastp);
        for (unsigned j = tid; j < T; j += SC2_THREADS) {
            unsigned p = spk[j];
            unsigned b = (unsigned)sbin[j];
            unsigned prevb = (ch == 0) ? 0u : snap[ch-1][b];
            unsigned pos = lbase[b] + prevb + (j - cstart[b]);
            if (pos < (unsigned)C) {
                ebuf[b * (unsigned)C + pos] = p;
            } else {
                unsigned oc = atomicAdd(ocur, 1u);
                if (oc < OVF_ENT) {
                    ovf[oc] = make_uint2(p & 0x3FFFFu,
                                         (b << BINSHIFT) | (p >> 18));
                }
            }
        }
        __syncthreads();
    }
}

// v12 accumA (kept): 2 blocks/bin, disjoint half-ranges, partials to pbuf.
__global__ __launch_bounds__(512) void accum_a_k(
        const uint4* __restrict__ xh,
        const unsigned* __restrict__ ebuf, const unsigned* __restrict__ gcount, int C,
        const unsigned* __restrict__ ocur, const uint2* __restrict__ ovf,
        float* __restrict__ pbuf, int nbins) {
    __shared__ unsigned srt[SRT_HALF];
    __shared__ unsigned cnt[BINSZ];
    __shared__ unsigned cstart[BINSZ];
    __shared__ unsigned wsum[4];
    __shared__ unsigned ovl[256];
    __shared__ unsigned ovn;
    float (*part)[BINSZ][TDIM] = (float(*)[BINSZ][TDIM])srt;
    int tid = threadIdx.x;
    int bh = blockIdx.x;
    int bin = bh >> 1;
    unsigned half = (unsigned)(bh & 1);
    if (tid < BINSZ) cnt[tid] = 0u;
    if (tid == 0) ovn = 0u;
    __syncthreads();

    unsigned gc = gcount[bin];
    unsigned m = gc < (unsigned)C ? gc : (unsigned)C;
    unsigned lo = half ? (m >> 1) : 0u;
    unsigned hi = half ? m : (m >> 1);
    unsigned e0 = (unsigned)bin * (unsigned)C;

    unsigned ed_[AH_EPT];
    unsigned rk_[AH_EPT];
#pragma unroll
    for (int k = 0; k < AH_EPT; k++) {
        ed_[k] = 0xFFFFFFFFu;
        unsigned i = lo + (unsigned)tid + (unsigned)k * 512u;
        if (i < hi) {
            unsigned v = __builtin_nontemporal_load(ebuf + e0 + i);
            ed_[k] = v;
            rk_[k] = atomicAdd(&cnt[v >> 18], 1u);
        }
    }
    if (half == 0u) {
        unsigned novf = *ocur;
        if (novf > OVF_ENT) novf = OVF_ENT;
        for (unsigned i = tid; i < novf; i += 512u) {
            uint2 e = ovf[i];
            if ((e.y >> BINSHIFT) == (unsigned)bin) {
                unsigned u = atomicAdd(&ovn, 1u);
                if (u < 256u) ovl[u] = ((e.y & (BINSZ-1)) << 18) | e.x;
            }
        }
    }
    __syncthreads();

    {
        unsigned v = (tid < BINSZ) ? cnt[tid] : 0u;
        int lane = tid & 63;
#pragma unroll
        for (int off = 1; off < 64; off <<= 1) {
            unsigned t = (unsigned)__shfl_up((int)v, off, 64);
            if (lane >= off) v += t;
        }
        if (tid < BINSZ && lane == 63) wsum[tid >> 6] = v;
        __syncthreads();
        if (tid < BINSZ) {
            unsigned add = 0;
            int w = tid >> 6;
#pragma unroll
            for (int ww = 0; ww < 3; ww++) if (ww < w) add += wsum[ww];
            cstart[tid] = v + add - cnt[tid];
        }
        __syncthreads();
    }

#pragma unroll
    for (int k = 0; k < AH_EPT; k++) {
        unsigned v = ed_[k];
        if (v != 0xFFFFFFFFu) srt[cstart[v >> 18] + rk_[k]] = v & 0x3FFFFu;
    }
    __syncthreads();

    int node = tid & (BINSZ - 1);
    int role = tid >> 8;
    float s0 = 0.f, s1 = 0.f, s2 = 0.f, s3 = 0.f, s4 = 0.f, s5 = 0.f;
    {
        unsigned c = cnt[node];
        unsigned b0 = cstart[node];
        unsigned h2 = c >> 1;
        unsigned j  = role ? h2 : 0u;
        unsigned je = role ? c : h2;
        for (; j + 8 <= je; j += 8) {
            unsigned i0 = srt[b0 + j],     i1 = srt[b0 + j + 1];
            unsigned i2 = srt[b0 + j + 2], i3 = srt[b0 + j + 3];
            unsigned i4 = srt[b0 + j + 4], i5 = srt[b0 + j + 5];
            unsigned i6 = srt[b0 + j + 6], i7 = srt[b0 + j + 7];
            uint4 r0 = xh[i0], r1 = xh[i1], r2 = xh[i2], r3 = xh[i3];
            uint4 r4 = xh[i4], r5 = xh[i5], r6 = xh[i6], r7 = xh[i7];
            add_row4(r0, s0, s1, s2, s3, s4, s5);
            add_row4(r1, s0, s1, s2, s3, s4, s5);
            add_row4(r2, s0, s1, s2, s3, s4, s5);
            add_row4(r3, s0, s1, s2, s3, s4, s5);
            add_row4(r4, s0, s1, s2, s3, s4, s5);
            add_row4(r5, s0, s1, s2, s3, s4, s5);
            add_row4(r6, s0, s1, s2, s3, s4, s5);
            add_row4(r7, s0, s1, s2, s3, s4, s5);
        }
        for (; j + 2 <= je; j += 2) {
            unsigned ia = srt[b0 + j], ib = srt[b0 + j + 1];
            uint4 ra = xh[ia], rb = xh[ib];
            add_row4(ra, s0, s1, s2, s3, s4, s5);
            add_row4(rb, s0, s1, s2, s3, s4, s5);
        }
        if (j < je) {
            uint4 ra = xh[srt[b0 + j]];
            add_row4(ra, s0, s1, s2, s3, s4, s5);
        }
        if (role == 0) {
            unsigned no = ovn < 256u ? ovn : 256u;
            for (unsigned q = 0; q < no; q++) {
                unsigned o = ovl[q];
                if ((int)(o >> 18) == node) {
                    uint4 rr = xh[o & 0x3FFFFu];
                    add_row4(rr, s0, s1, s2, s3, s4, s5);
                }
            }
        }
    }
    __syncthreads();
    part[role][node][0] = s0; part[role][node][1] = s1; part[role][node][2] = s2;
    part[role][node][3] = s3; part[role][node][4] = s4; part[role][node][5] = s5;
    __syncthreads();

    float* pb = pbuf + (size_t)bh * PB_NODE;
    for (int j = tid; j < PB_NODE; j += 512) {
        int nd = j / TDIM, d = j - nd * TDIM;
        pb[j] = part[0][nd][d] + part[1][nd][d];
    }
}

// v12 accumB (kept): fully-parallel fused MLP over nodes.
__global__ __launch_bounds__(256) void accum_b_k(
        const float* __restrict__ xm, const float* __restrict__ pbuf,
        const float* __restrict__ H, const float* __restrict__ W,
        float* __restrict__ facc, int N) {
    __shared__ float sH[LDIM * TDIM * MDIM];
    __shared__ float sW[LDIM];
    __shared__ float sred[4][MDIM];
    int tid = threadIdx.x;
    for (int i = tid; i < LDIM * TDIM * MDIM; i += 256) sH[i] = H[i];
    if (tid < LDIM) sW[tid] = W[tid];
    __syncthreads();

    int n = blockIdx.x * 256 + tid;
    float fs[MDIM];
#pragma unroll
    for (int mm = 0; mm < MDIM; mm++) fs[mm] = 0.f;

    if (n < N) {
        int bin = n >> BINSHIFT;
        int node = n & (BINSZ - 1);
        const float* p0 = pbuf + (size_t)(bin * 2 + 0) * PB_NODE + node * TDIM;
        const float* p1 = pbuf + (size_t)(bin * 2 + 1) * PB_NODE + node * TDIM;
        const float2* xr = (const float2*)(xm + (size_t)n * TDIM);
        float2 x0 = xr[0], x1 = xr[1], x2 = xr[2];
        float v[TDIM];
        v[0] = x0.x + p0[0] + p1[0];
        v[1] = x0.y + p0[1] + p1[1];
        v[2] = x1.x + p0[2] + p1[2];
        v[3] = x1.y + p0[3] + p1[3];
        v[4] = x2.x + p0[4] + p1[4];
        v[5] = x2.y + p0[5] + p1[5];

#pragma unroll
        for (int l = 0; l < LDIM; l++) {
            float z[MDIM];
#pragma unroll
            for (int mm = 0; mm < MDIM; mm++) {
                float a2 = 0.f;
#pragma unroll
                for (int t = 0; t < TDIM; t++) a2 += v[t] * sH[(l * TDIM + t) * MDIM + mm];
                z[mm] = a2;
            }
            float wl = sW[l];
            float mx = -1e30f;
#pragma unroll
            for (int mm = 0; mm < MDIM; mm++) {
                float sg = wl / (1.f + __expf(-z[mm]));
                z[mm] = sg;
                mx = fmaxf(mx, sg);
            }
            float se = 0.f;
#pragma unroll
            for (int mm = 0; mm < MDIM; mm++) {
                float e = __expf(z[mm] - mx);
                z[mm] = e;
                se += e;
            }
            float inv = 1.f / se;
#pragma unroll
            for (int mm = 0; mm < MDIM; mm++) fs[mm] += z[mm] * inv;
        }
    }

#pragma unroll
    for (int mm = 0; mm < MDIM; mm++) {
        float v = fs[mm];
#pragma unroll
        for (int off = 32; off > 0; off >>= 1) v += __shfl_down(v, off, 64);
        fs[mm] = v;
    }
    int wave = tid >> 6, lane = tid & 63;
    if (lane == 0) {
#pragma unroll
        for (int mm = 0; mm < MDIM; mm++) sred[wave][mm] = fs[mm];
    }
    __syncthreads();
    if (tid < MDIM) {
        float s = 0.f;
#pragma unroll
        for (int w = 0; w < 4; w++) s += sred[w][tid];
        atomicAdd(facc + tid, s);
    }
}

// v11 accum2 (kept as fallback when pbuf doesn't fit in workspace)
__global__ __launch_bounds__(AC_BLOCK) void accum2_k(
        const float* __restrict__ xm, const uint4* __restrict__ xh,
        const unsigned* __restrict__ ebuf, const unsigned* __restrict__ gcount, int C,
        const unsigned* __restrict__ ocur, const uint2* __restrict__ ovf,
        const float* __restrict__ H, const float* __restrict__ W,
        float* __restrict__ facc, int N) {
    __shared__ unsigned srt[AC_CAP];
    __shared__ unsigned cnt[BINSZ];
    __shared__ unsigned cstart[BINSZ];
    __shared__ unsigned wsum[8];
    __shared__ unsigned ovl[256];
    __shared__ unsigned ovn;
    __shared__ float sH[LDIM * TDIM * MDIM];
    __shared__ float sW[LDIM];
    __shared__ float sred[AC_BLOCK / 64][MDIM];
    float (*part)[BINSZ][TDIM] = (float(*)[BINSZ][TDIM])srt;
    int tid = threadIdx.x;
    int bin = blockIdx.x;
    for (int i = tid; i < LDIM * TDIM * MDIM; i += AC_BLOCK) sH[i] = H[i];
    if (tid < LDIM) sW[tid] = W[tid];
    if (tid < BINSZ) cnt[tid] = 0u;
    if (tid == 0) ovn = 0u;
    __syncthreads();

    unsigned gc = gcount[bin];
    unsigned m = gc < (unsigned)C ? gc : (unsigned)C;
    unsigned e0 = (unsigned)bin * (unsigned)C;
    int nbase = bin << BINSHIFT;

    unsigned ed_[AC_EPT];
    unsigned rk_[AC_EPT];
#pragma unroll
    for (int k = 0; k < AC_EPT; k++) {
        unsigned i = (unsigned)tid + (unsigned)k * AC_BLOCK;
        if (i < m) {
            unsigned v = __builtin_nontemporal_load(ebuf + e0 + i);
            ed_[k] = v;
            rk_[k] = atomicAdd(&cnt[v >> 18], 1u);
        }
    }
    {
        unsigned novf = *ocur;
        if (novf > OVF_ENT) novf = OVF_ENT;
        for (unsigned i = tid; i < novf; i += AC_BLOCK) {
            uint2 e = ovf[i];
            if ((e.y >> BINSHIFT) == (unsigned)bin) {
                unsigned u = atomicAdd(&ovn, 1u);
                if (u < 256u) ovl[u] = ((e.y & (BINSZ-1)) << 18) | e.x;
            }
        }
    }
    __syncthreads();

    {
        unsigned v = (tid < BINSZ) ? cnt[tid] : 0u;
        int lane = tid & 63;
#pragma unroll
        for (int off = 1; off < 64; off <<= 1) {
            unsigned t = (unsigned)__shfl_up((int)v, off, 64);
            if (lane >= off) v += t;
        }
        if (tid < BINSZ && lane == 63) wsum[tid >> 6] = v;
        __syncthreads();
        if (tid < BINSZ) {
            unsigned add = 0;
            int w = tid >> 6;
#pragma unroll
            for (int ww = 0; ww < 3; ww++) if (ww < w) add += wsum[ww];
            cstart[tid] = v + add - cnt[tid];
        }
        __syncthreads();
    }

#pragma unroll
    for (int k = 0; k < AC_EPT; k++) {
        unsigned i = (unsigned)tid + (unsigned)k * AC_BLOCK;
        if (i < m) {
            unsigned v = ed_[k];
            srt[cstart[v >> 18] + rk_[k]] = v & 0x3FFFFu;
        }
    }
    __syncthreads();

    int node = tid & (BINSZ - 1);
    int role = tid >> 8;
    int n = nbase + node;
    float s0 = 0.f, s1 = 0.f, s2 = 0.f, s3 = 0.f, s4 = 0.f, s5 = 0.f;
    if (n < N) {
        unsigned c = cnt[node];
        unsigned b0 = cstart[node];
        unsigned h = c >> 1;
        unsigned j  = role ? h : 0u;
        unsigned je = role ? c : h;
        for (; j + 8 <= je; j += 8) {
            unsigned i0 = srt[b0 + j],     i1 = srt[b0 + j + 1];
            unsigned i2 = srt[b0 + j + 2], i3 = srt[b0 + j + 3];
            unsigned i4 = srt[b0 + j + 4], i5 = srt[b0 + j + 5];
            unsigned i6 = srt[b0 + j + 6], i7 = srt[b0 + j + 7];
            uint4 r0 = xh[i0], r1 = xh[i1], r2 = xh[i2], r3 = xh[i3];
            uint4 r4 = xh[i4], r5 = xh[i5], r6 = xh[i6], r7 = xh[i7];
            add_row4(r0, s0, s1, s2, s3, s4, s5);
            add_row4(r1, s0, s1, s2, s3, s4, s5);
            add_row4(r2, s0, s1, s2, s3, s4, s5);
            add_row4(r3, s0, s1, s2, s3, s4, s5);
            add_row4(r4, s0, s1, s2, s3, s4, s5);
            add_row4(r5, s0, s1, s2, s3, s4, s5);
            add_row4(r6, s0, s1, s2, s3, s4, s5);
            add_row4(r7, s0, s1, s2, s3, s4, s5);
        }
        for (; j + 2 <= je; j += 2) {
            unsigned ia = srt[b0 + j], ib = srt[b0 + j + 1];
            uint4 ra = xh[ia], rb = xh[ib];
            add_row4(ra, s0, s1, s2, s3, s4, s5);
            add_row4(rb, s0, s1, s2, s3, s4, s5);
        }
        if (j < je) {
            uint4 ra = xh[srt[b0 + j]];
            add_row4(ra, s0, s1, s2, s3, s4, s5);
        }
        if (role == 0) {
            unsigned no = ovn < 256u ? ovn : 256u;
            for (unsigned q = 0; q < no; q++) {
                unsigned o = ovl[q];
                if ((int)(o >> 18) == node) {
                    uint4 rr = xh[o & 0x3FFFFu];
                    add_row4(rr, s0, s1, s2, s3, s4, s5);
                }
            }
        }
    }
    __syncthreads();
    part[role][node][0] = s0; part[role][node][1] = s1; part[role][node][2] = s2;
    part[role][node][3] = s3; part[role][node][4] = s4; part[role][node][5] = s5;
    __syncthreads();

    float fs[MDIM];
#pragma unroll
    for (int mm = 0; mm < MDIM; mm++) fs[mm] = 0.f;

    if (n < N) {
        float v[TDIM];
        const float2* xr = (const float2*)(xm + (size_t)n * TDIM);
        float2 x0 = xr[0], x1 = xr[1], x2 = xr[2];
        v[0] = x0.x + part[0][node][0] + part[1][node][0];
        v[1] = x0.y + part[0][node][1] + part[1][node][1];
        v[2] = x1.x + part[0][node][2] + part[1][node][2];
        v[3] = x1.y + part[0][node][3] + part[1][node][3];
        v[4] = x2.x + part[0][node][4] + part[1][node][4];
        v[5] = x2.y + part[0][node][5] + part[1][node][5];

        int lb = role << 1;
#pragma unroll
        for (int li = 0; li < 2; li++) {
            int l = lb + li;
            float z[MDIM];
#pragma unroll
            for (int mm = 0; mm < MDIM; mm++) {
                float a2 = 0.f;
#pragma unroll
                for (int t = 0; t < TDIM; t++) a2 += v[t] * sH[(l * TDIM + t) * MDIM + mm];
                z[mm] = a2;
            }
            float wl = sW[l];
            float mx = -1e30f;
#pragma unroll
            for (int mm = 0; mm < MDIM; mm++) {
                float sg = wl / (1.f + __expf(-z[mm]));
                z[mm] = sg;
                mx = fmaxf(mx, sg);
            }
            float se = 0.f;
#pragma unroll
            for (int mm = 0; mm < MDIM; mm++) {
                float e = __expf(z[mm] - mx);
                z[mm] = e;
                se += e;
            }
            float inv = 1.f / se;
#pragma unroll
            for (int mm = 0; mm < MDIM; mm++) fs[mm] += z[mm] * inv;
        }
    }

#pragma unroll
    for (int mm = 0; mm < MDIM; mm++) {
        float v = fs[mm];
#pragma unroll
        for (int off = 32; off > 0; off >>= 1) v += __shfl_down(v, off, 64);
        fs[mm] = v;
    }
    int wave = tid >> 6, lane = tid & 63;
    if (lane == 0) {
#pragma unroll
        for (int mm = 0; mm < MDIM; mm++) sred[wave][mm] = fs[mm];
    }
    __syncthreads();
    if (tid < MDIM) {
        float s = 0.f;
#pragma unroll
        for (int w = 0; w < AC_BLOCK / 64; w++) s += sred[w][tid];
        atomicAdd(facc + tid, s);
    }
}

// ================= TIER 2: legacy hist/scan path =================

__global__ __launch_bounds__(256) void prep_k(const float* __restrict__ xm, int N,
                                              uint4* __restrict__ xh,
                                              const int* __restrict__ dst, int E,
                                              unsigned* __restrict__ hist, int nbins) {
    __shared__ unsigned lh[MAXBINS];
    for (int i = threadIdx.x; i < MAXBINS; i += blockDim.x) lh[i] = 0u;
    __syncthreads();
    int gid = blockIdx.x * blockDim.x + threadIdx.x;
    int gstride = gridDim.x * blockDim.x;
    for (int n = gid; n < N; n += gstride) {
        const float2* r = (const float2*)(xm + (size_t)n * TDIM);
        float2 a = r[0], b = r[1], c = r[2];
        __half2 h0 = __floats2half2_rn(a.x, a.y);
        __half2 h1 = __floats2half2_rn(b.x, b.y);
        __half2 h2 = __floats2half2_rn(c.x, c.y);
        uint4 o;
        o.x = *(unsigned*)&h0; o.y = *(unsigned*)&h1; o.z = *(unsigned*)&h2; o.w = 0u;
        xh[n] = o;
    }
    int e4 = E >> 2;
    const int4* d4p = (const int4*)dst;
    for (int i = gid; i < e4; i += gstride) {
        int4 d = d4p[i];
        atomicAdd(&lh[((unsigned)d.x) >> BINSHIFT], 1u);
        atomicAdd(&lh[((unsigned)d.y) >> BINSHIFT], 1u);
        atomicAdd(&lh[((unsigned)d.z) >> BINSHIFT], 1u);
        atomicAdd(&lh[((unsigned)d.w) >> BINSHIFT], 1u);
    }
    for (int e = (e4 << 2) + gid; e < E; e += gstride)
        atomicAdd(&lh[((unsigned)dst[e]) >> BINSHIFT], 1u);
    __syncthreads();
    for (int i = threadIdx.x; i < nbins; i += blockDim.x)
        if (lh[i]) atomicAdd(&hist[i], lh[i]);
}

__global__ __launch_bounds__(MAXBINS) void scan_k(const unsigned* __restrict__ hist,
                                                  unsigned* __restrict__ offsets,
                                                  unsigned* __restrict__ gfill, int nbins) {
    __shared__ unsigned buf[2][MAXBINS];
    int t = threadIdx.x;
    buf[0][t] = (t < nbins) ? hist[t] : 0u;
    __syncthreads();
    int cur = 0;
    for (int off = 1; off < MAXBINS; off <<= 1) {
        unsigned v = buf[cur][t];
        if (t >= off) v += buf[cur][t - off];
        buf[cur ^ 1][t] = v;
        __syncthreads();
        cur ^= 1;
    }
    if (t < nbins) {
        unsigned ex = t ? buf[cur][t - 1] : 0u;
        offsets[t] = ex;
        gfill[t] = ex;
    }
    if (t == 0) offsets[nbins] = buf[cur][nbins - 1];
}

__global__ __launch_bounds__(SC_BLOCK) void scatter_k(const int* __restrict__ src,
                                                      const int* __restrict__ dst, int E,
                                                      unsigned* __restrict__ gfill,
                                                      unsigned* __restrict__ ebuf, int nbins) {
    __shared__ unsigned lcount[MAXBINS];
    __shared__ unsigned lbase[MAXBINS];
    for (int i = threadIdx.x; i < MAXBINS; i += SC_BLOCK) lcount[i] = 0u;
    __syncthreads();
    int base = blockIdx.x * SC_EPB + threadIdx.x * SC_EPT;
    int s[SC_EPT], d[SC_EPT];
    unsigned rk[SC_EPT];
#pragma unroll
    for (int q = 0; q < SC_EPT / 4; q++) {
        int e = base + q * 4;
        if (e + 3 < E) {
            int4 s4 = *(const int4*)(src + e);
            int4 d4 = *(const int4*)(dst + e);
            s[q*4+0] = s4.x; s[q*4+1] = s4.y; s[q*4+2] = s4.z; s[q*4+3] = s4.w;
            d[q*4+0] = d4.x; d[q*4+1] = d4.y; d[q*4+2] = d4.z; d[q*4+3] = d4.w;
        } else {
#pragma unroll
            for (int k = 0; k < 4; k++) {
                int ee = e + k;
                s[q*4+k] = (ee < E) ? src[ee] : -1;
                d[q*4+k] = (ee < E) ? dst[ee] : 0;
            }
        }
    }
#pragma unroll
    for (int k = 0; k < SC_EPT; k++)
        if (s[k] >= 0) rk[k] = atomicAdd(&lcount[((unsigned)d[k]) >> BINSHIFT], 1u);
    __syncthreads();
    for (int i = threadIdx.x; i < nbins; i += SC_BLOCK) {
        unsigned c = lcount[i];
        if (c) lbase[i] = atomicAdd(&gfill[i], c);
    }
    __syncthreads();
#pragma unroll
    for (int k = 0; k < SC_EPT; k++) {
        if (s[k] >= 0) {
            unsigned du = (unsigned)d[k];
            unsigned b = du >> BINSHIFT;
            unsigned pack = ((du & (BINSZ - 1)) << 18) | (unsigned)s[k];
            ebuf[lbase[b] + rk[k]] = pack;
        }
    }
}

__global__ __launch_bounds__(AC_BLOCK) void accum_node_k(
        const float* __restrict__ xm, const uint4* __restrict__ xh,
        const unsigned* __restrict__ ebuf, const unsigned* __restrict__ offsets,
        const float* __restrict__ H, const float* __restrict__ W,
        float* __restrict__ facc, int N) {
    __shared__ unsigned srt[AC_CAP];
    __shared__ unsigned cnt[BINSZ];
    __shared__ unsigned tmp[BINSZ];
    __shared__ unsigned cstart[BINSZ];
    __shared__ float sH[LDIM * TDIM * MDIM];
    __shared__ float sW[LDIM];
    __shared__ float sred[AC_BLOCK / 64][MDIM];
    int tid = threadIdx.x;
    int bin = blockIdx.x;
    for (int i = tid; i < LDIM * TDIM * MDIM; i += AC_BLOCK) sH[i] = H[i];
    if (tid < LDIM) sW[tid] = W[tid];
    if (tid < BINSZ) cnt[tid] = 0u;
    __syncthreads();

    unsigned e0 = offsets[bin], e1 = offsets[bin + 1];
    unsigned total = e1 - e0;
    unsigned m = total < AC_CAP ? total : AC_CAP;
    int nbase = bin << BINSHIFT;

    unsigned ed_[AC_EPT];
    unsigned rk_[AC_EPT];
#pragma unroll
    for (int k = 0; k < AC_EPT; k++) {
        unsigned idx = e0 + (unsigned)tid + (unsigned)k * AC_BLOCK;
        if (idx < e0 + m) {
            unsigned v = ebuf[idx];
            ed_[k] = v;
            rk_[k] = atomicAdd(&cnt[v >> 18], 1u);
        }
    }
    __syncthreads();

    if (tid < BINSZ) tmp[tid] = cnt[tid];
    __syncthreads();
    for (int off = 1; off < BINSZ; off <<= 1) {
        unsigned v = 0;
        if (tid < BINSZ) { v = tmp[tid]; if (tid >= off) v += tmp[tid - off]; }
        __syncthreads();
        if (tid < BINSZ) tmp[tid] = v;
        __syncthreads();
    }
    if (tid < BINSZ) cstart[tid] = tmp[tid] - cnt[tid];
    __syncthreads();

#pragma unroll
    for (int k = 0; k < AC_EPT; k++) {
        unsigned idx = e0 + (unsigned)tid + (unsigned)k * AC_BLOCK;
        if (idx < e0 + m) {
            unsigned v = ed_[k];
            srt[cstart[v >> 18] + rk_[k]] = v & 0x3FFFFu;
        }
    }
    __syncthreads();

    float fs[MDIM];
#pragma unroll
    for (int mm = 0; mm < MDIM; mm++) fs[mm] = 0.f;

    int n = nbase + tid;
    if (tid < BINSZ && n < N) {
        float s0 = 0.f, s1 = 0.f, s2 = 0.f, s3 = 0.f, s4 = 0.f, s5 = 0.f;
        unsigned c = cnt[tid];
        unsigned b0 = cstart[tid];
        unsigned j = 0;
        for (; j + 2 <= c; j += 2) {
            unsigned sa = srt[b0 + j], sb = srt[b0 + j + 1];
            uint4 ra = xh[sa];
            uint4 rb = xh[sb];
            add_row4(ra, s0, s1, s2, s3, s4, s5);
            add_row4(rb, s0, s1, s2, s3, s4, s5);
        }
        if (j < c) {
            uint4 ra = xh[srt[b0 + j]];
            add_row4(ra, s0, s1, s2, s3, s4, s5);
        }
        for (unsigned idx = e0 + m; idx < e1; idx++) {
            unsigned v = ebuf[idx];
            if ((int)(v >> 18) == tid) {
                uint4 ra = xh[v & 0x3FFFFu];
                add_row4(ra, s0, s1, s2, s3, s4, s5);
            }
        }

        float v[TDIM];
        const float2* xr = (const float2*)(xm + (size_t)n * TDIM);
        float2 x0 = xr[0], x1 = xr[1], x2 = xr[2];
        v[0] = x0.x + s0; v[1] = x0.y + s1;
        v[2] = x1.x + s2; v[3] = x1.y + s3;
        v[4] = x2.x + s4; v[5] = x2.y + s5;

#pragma unroll
        for (int l = 0; l < LDIM; l++) {
            float z[MDIM];
#pragma unroll
            for (int mm = 0; mm < MDIM; mm++) {
                float a2 = 0.f;
#pragma unroll
                for (int t = 0; t < TDIM; t++) a2 += v[t] * sH[(l * TDIM + t) * MDIM + mm];
                z[mm] = a2;
            }
            float wl = sW[l];
            float mx = -1e30f;
#pragma unroll
            for (int mm = 0; mm < MDIM; mm++) {
                float sg = wl / (1.f + __expf(-z[mm]));
                z[mm] = sg;
                mx = fmaxf(mx, sg);
            }
            float se = 0.f;
#pragma unroll
            for (int mm = 0; mm < MDIM; mm++) {
                float e = __expf(z[mm] - mx);
                z[mm] = e;
                se += e;
            }
            float inv = 1.f / se;
#pragma unroll
            for (int mm = 0; mm < MDIM; mm++) fs[mm] += z[mm] * inv;
        }
    }

#pragma unroll
    for (int mm = 0; mm < MDIM; mm++) {
        float v = fs[mm];
#pragma unroll
        for (int off = 32; off > 0; off >>= 1) v += __shfl_down(v, off, 64);
        fs[mm] = v;
    }
    int wave = tid >> 6, lane = tid & 63;
    if (lane == 0) {
#pragma unroll
        for (int mm = 0; mm < MDIM; mm++) sred[wave][mm] = fs[mm];
    }
    __syncthreads();
    if (tid < MDIM) {
        float s = 0.f;
#pragma unroll
        for (int w = 0; w < AC_BLOCK / 64; w++) s += sred[w][tid];
        atomicAdd(facc + tid, s);
    }
}

// ---------------- final tiny perceptron ----------------
__global__ void finalize_k(const float* __restrict__ facc,
                           const float* __restrict__ xg,
                           const float* __restrict__ gW,
                           const float* __restrict__ gb,
                           const float* __restrict__ mW,
                           const float* __restrict__ mb,
                           float* __restrict__ out) {
    if (threadIdx.x == 0 && blockIdx.x == 0) {
        float merged[MDIM + GLOD];
#pragma unroll
        for (int m = 0; m < MDIM; m++) merged[m] = facc[m];
        for (int j = 0; j < GLOD; j++) {
            float a = gb[j];
            for (int i = 0; i < GIND; i++) a += xg[i] * gW[j * GIND + i];
            merged[MDIM + j] = 1.f / (1.f + __expf(-a));
        }
        float lg[3];
        float mx = -1e30f;
        for (int k = 0; k < 3; k++) {
            float a = mb[k];
            for (int j = 0; j < MDIM + GLOD; j++) a += merged[j] * mW[k * (MDIM + GLOD) + j];
            lg[k] = a;
            mx = fmaxf(mx, a);
        }
        float se = 0.f;
        for (int k = 0; k < 3; k++) { lg[k] = __expf(lg[k] - mx); se += lg[k]; }
        float inv = 1.f / se;
        for (int k = 0; k < 3; k++) out[k] = lg[k] * inv;
    }
}

// ---------------- TIER 3 fallback: global-atomic path ----------------
__global__ void fb_zero_k(float* __restrict__ ws, int n) {
    int i = blockIdx.x * blockDim.x + threadIdx.x;
    if (i < n) ws[i] = 0.f;
}

__global__ void fb_edge_scatter_k(const float* __restrict__ xm,
                                  const int* __restrict__ src,
                                  const int* __restrict__ dst,
                                  float* __restrict__ neigh, int E) {
    int e = blockIdx.x * blockDim.x + threadIdx.x;
    if (e >= E) return;
    int s = src[e], d = dst[e];
    const float2* r = (const float2*)(xm + (size_t)s * TDIM);
    float2 a = r[0], b = r[1], c = r[2];
    float* o = neigh + (size_t)d * TDIM;
    atomicAdd(o + 0, a.x); atomicAdd(o + 1, a.y);
    atomicAdd(o + 2, b.x); atomicAdd(o + 3, b.y);
    atomicAdd(o + 4, c.x); atomicAdd(o + 5, c.y);
}

__global__ __launch_bounds__(256) void fb_node_k(
        const float* __restrict__ xm, const float* __restrict__ neigh,
        const float* __restrict__ H, const float* __restrict__ W,
        float* __restrict__ facc, int N) {
    __shared__ float sH[LDIM * TDIM * MDIM];
    __shared__ float sW[LDIM];
    __shared__ float sred[4][MDIM];
    int tid = threadIdx.x;
    for (int i = tid; i < LDIM * TDIM * MDIM; i += blockDim.x) sH[i] = H[i];
    if (tid < LDIM) sW[tid] = W[tid];
    __syncthreads();
    float fs[MDIM];
#pragma unroll
    for (int m = 0; m < MDIM; m++) fs[m] = 0.f;
    for (int n = blockIdx.x * blockDim.x + tid; n < N; n += gridDim.x * blockDim.x) {
        float v[TDIM];
        const float2* xr = (const float2*)(xm + (size_t)n * TDIM);
        const float2* nr = (const float2*)(neigh + (size_t)n * TDIM);
#pragma unroll
        for (int t2 = 0; t2 < 3; t2++) {
            float2 a = xr[t2], b = nr[t2];
            v[2 * t2 + 0] = a.x + b.x;
            v[2 * t2 + 1] = a.y + b.y;
        }
#pragma unroll
        for (int l = 0; l < LDIM; l++) {
            float z[MDIM];
#pragma unroll
            for (int m = 0; m < MDIM; m++) {
                float a2 = 0.f;
#pragma unroll
                for (int t = 0; t < TDIM; t++) a2 += v[t] * sH[(l * TDIM + t) * MDIM + m];
                z[m] = a2;
            }
            float wl = sW[l], mx = -1e30f;
#pragma unroll
            for (int m = 0; m < MDIM; m++) { float sg = wl / (1.f + __expf(-z[m])); z[m] = sg; mx = fmaxf(mx, sg); }
            float se = 0.f;
#pragma unroll
            for (int m = 0; m < MDIM; m++) { float e = __expf(z[m] - mx); z[m] = e; se += e; }
            float inv = 1.f / se;
#pragma unroll
            for (int m = 0; m < MDIM; m++) fs[m] += z[m] * inv;
        }
    }
#pragma unroll
    for (int m = 0; m < MDIM; m++) {
        float v = fs[m];
#pragma unroll
        for (int off = 32; off > 0; off >>= 1) v += __shfl_down(v, off, 64);
        fs[m] = v;
    }
    int wave = tid >> 6, lane = tid & 63;
    if (lane == 0) {
#pragma unroll
        for (int m = 0; m < MDIM; m++) sred[wave][m] = fs[m];
    }
    __syncthreads();
    if (tid < MDIM) {
        float s = sred[0][tid] + sred[1][tid] + sred[2][tid] + sred[3][tid];
        atomicAdd(facc + tid, s);
    }
}

extern "C" void kernel_launch(void* const* d_in, const int* in_sizes, int n_in,
                              void* d_out, int out_size, void* d_ws, size_t ws_size,
                              hipStream_t stream) {
    const float* xm  = (const float*)d_in[0];
    const float* xg  = (const float*)d_in[1];
    const int*   src = (const int*)d_in[2];
    const int*   dst = (const int*)d_in[3];
    const float* H   = (const float*)d_in[4];
    const float* W   = (const float*)d_in[5];
    const float* gW  = (const float*)d_in[6];
    const float* gb  = (const float*)d_in[7];
    const float* mW  = (const float*)d_in[8];
    const float* mb  = (const float*)d_in[9];
    float* out = (float*)d_out;

    int N = in_sizes[0] / TDIM;
    int E = in_sizes[2];
    int nbins = (N + BINSZ - 1) >> BINSHIFT;
    size_t ws_words = ws_size / 4;
    size_t xh_words = (size_t)N * 4;
    size_t pbuf_words = (size_t)nbins * 2 * PB_NODE;

    double mu = (double)E / nbins;
    long Cmin = (long)(mu + 4.0 * sqrt(mu) + 32.0);
    int NQ = E >> 2;
    int QPB = (NQ + SC2_BLOCKS - 1) / SC2_BLOCKS;
    bool qpb_ok = QPB <= SC2_KQ * SC2_THREADS;

    // ---- tier 1a: split accum (needs pbuf) ----
    long fixed_s = (long)(xh_words + META2 + (size_t)OVF_ENT * 2 + pbuf_words);
    long avail_s = (long)ws_words - fixed_s;
    long Cs = avail_s > 0 ? (avail_s / nbins) & ~3L : 0;
    if (Cs > AC_CAP) Cs = AC_CAP;
    bool ok1s = (Cs >= Cmin) && nbins <= MAXBINS && N <= (1 << 18) && qpb_ok;

    // ---- tier 1b: v11 single-kernel accum ----
    long fixed = (long)(xh_words + META2 + (size_t)OVF_ENT * 2);
    long avail = (long)ws_words - fixed;
    long C = avail > 0 ? (avail / nbins) & ~3L : 0;
    if (C > AC_CAP) C = AC_CAP;
    bool ok1 = (C >= Cmin) && nbins <= MAXBINS && N <= (1 << 18) && qpb_ok;

    // ---- tier 2: legacy hist/scan ----
    size_t meta_words2 = MAXBINS + (MAXBINS + 1) + MAXBINS + 16;
    size_t need2 = (xh_words + (size_t)E + meta_words2) * 4;
    bool ok2 = ws_size >= need2 && nbins <= MAXBINS && N <= (1 << 18);

    if (ok1s) {
        uint4*    xh     = (uint4*)d_ws;
        unsigned* ebuf   = (unsigned*)d_ws + xh_words;
        unsigned* gcount = ebuf + (size_t)nbins * Cs;
        unsigned* ocur   = gcount + MAXBINS;
        float*    facc   = (float*)(ocur + 16);
        uint2*    ovf    = (uint2*)(gcount + META2);
        float*    pbuf   = (float*)(gcount + META2 + (size_t)OVF_ENT * 2);

        zero32_k<<<(META2 + 255) / 256, 256, 0, stream>>>(gcount, META2);
        scat2_k<<<SC2_BLOCKS, SC2_THREADS, 0, stream>>>(xm, N, xh, src, dst, E, NQ, QPB,
                                                        gcount, ebuf, (int)Cs, nbins, ovf, ocur);
        accum_a_k<<<nbins * 2, 512, 0, stream>>>(xh, ebuf, gcount, (int)Cs, ocur, ovf,
                                                 pbuf, nbins);
        accum_b_k<<<(N + 255) / 256, 256, 0, stream>>>(xm, pbuf, H, W, facc, N);
        finalize_k<<<1, 64, 0, stream>>>(facc, xg, gW, gb, mW, mb, out);
    } else if (ok1) {
        uint4*    xh     = (uint4*)d_ws;
        unsigned* ebuf   = (unsigned*)d_ws + xh_words;
        unsigned* gcount = ebuf + (size_t)nbins * C;
        unsigned* ocur   = gcount + MAXBINS;
        float*    facc   = (float*)(ocur + 16);
        uint2*    ovf    = (uint2*)(gcount + META2);

        zero32_k<<<(META2 + 255) / 256, 256, 0, stream>>>(gcount, META2);
        scat2_k<<<SC2_BLOCKS, SC2_THREADS, 0, stream>>>(xm, N, xh, src, dst, E, NQ, QPB,
                                                        gcount, ebuf, (int)C, nbins, ovf, ocur);
        accum2_k<<<nbins, AC_BLOCK, 0, stream>>>(xm, xh, ebuf, gcount, (int)C, ocur, ovf,
                                                 H, W, facc, N);
        finalize_k<<<1, 64, 0, stream>>>(facc, xg, gW, gb, mW, mb, out);
    } else if (ok2) {
        uint4*    xh      = (uint4*)d_ws;
        unsigned* ebuf    = (unsigned*)d_ws + xh_words;
        unsigned* hist    = ebuf + (size_t)E;
        unsigned* offsets = hist + MAXBINS;
        unsigned* gfill   = offsets + MAXBINS + 1;
        float*    facc    = (float*)(gfill + MAXBINS);

        zero32_k<<<(int)((meta_words2 + 255) / 256), 256, 0, stream>>>(hist, (int)meta_words2);
        prep_k<<<1024, 256, 0, stream>>>(xm, N, xh, dst, E, hist, nbins);
        scan_k<<<1, MAXBINS, 0, stream>>>(hist, offsets, gfill, nbins);
        scatter_k<<<(E + SC_EPB - 1) / SC_EPB, SC_BLOCK, 0, stream>>>(src, dst, E, gfill, ebuf, nbins);
        accum_node_k<<<nbins, AC_BLOCK, 0, stream>>>(xm, xh, ebuf, offsets, H, W, facc, N);
        finalize_k<<<1, 64, 0, stream>>>(facc, xg, gW, gb, mW, mb, out);
    } else {
        float* neigh = (float*)d_ws;
        float* facc  = neigh + (size_t)N * TDIM;
        int zn = N * TDIM + 16;
        fb_zero_k<<<(zn + 255) / 256, 256, 0, stream>>>(neigh, zn);
        fb_edge_scatter_k<<<(E + 255) / 256, 256, 0, stream>>>(xm, src, dst, neigh, E);
        fb_node_k<<<256, 256, 0, stream>>>(xm, neigh, H, W, facc, N);
        finalize_k<<<1, 64, 0, stream>>>(facc, xg, gW, gb, mW, mb, out);
    }
}

// Round 16
// 113.558 us; speedup vs baseline: 1.1250x; 1.0211x over previous
//
#include <hip/hip_runtime.h>
#include <hip/hip_fp16.h>
#include <math.h>

#define TDIM 6
#define MDIM 10
#define LDIM 4
#define GIND 14
#define GLOD 10

#define BINSHIFT 8
#define BINSZ 256            // nodes per bin
#define MAXBINS 1024         // supports N up to 262144 (pack limit: src < 2^18)

// ---- fixed-capacity scatter path (r13 best-measured config: 113.6us) ----
// LDS-sorted coalesced ebuf write-out (fixes 5.4x temporal write amplification,
// r11) + slim u16 bin-id staging (r13: 50.3KB LDS). 512 blocks: r14 showed
// per-block fixed bin-array work makes grid a work multiplier; 512 is the
// measured sweet spot.
#define SC2_BLOCKS 512
#define SC2_THREADS 512
#define SC2_CHQ 1408         // quads per chunk (5632 edges)
#define SC2_CHUNKS 3         // QPB <= 4224 quads -> E <= 8.6M
#define SC2_TQ 3             // ceil(SC2_CHQ / SC2_THREADS)
#define OVF_ENT 16384
#define META2 2048           // gcount[1024] + ocur + facc + pad

// ---- accum params ----
#define SC_BLOCK 512
#define SC_EPT 32
#define SC_EPB (SC_BLOCK * SC_EPT)
#define AC_BLOCK 512
#define AC_CAP 8704          // mean 8192 + 5.7 sigma; overflow handled via ovf path
#define AC_EPT 17            // AC_CAP / AC_BLOCK

// ---- split-accum params (v12 winner) ----
#define SRT_HALF 4352        // ceil(AC_CAP/2); 17.4 KB LDS
#define AH_EPT 9             // ceil(SRT_HALF / 512)
#define PB_NODE (BINSZ * TDIM)   // 1536 floats per (bin,half)

// ---------------- small utility ----------------
__global__ void zero32_k(unsigned* __restrict__ p, int n) {
    int i = blockIdx.x * blockDim.x + threadIdx.x;
    if (i < n) p[i] = 0u;
}

__device__ __forceinline__ void add_row4(uint4 r, float& s0, float& s1, float& s2,
                                         float& s3, float& s4, float& s5) {
    float2 a0 = __half22float2(*(__half2*)&r.x);
    float2 a1 = __half22float2(*(__half2*)&r.y);
    float2 a2 = __half22float2(*(__half2*)&r.z);
    s0 += a0.x; s1 += a0.y; s2 += a1.x; s3 += a1.y; s4 += a2.x; s5 += a2.y;
}

// ================= TIER 1: fixed-capacity bins =================

__global__ __launch_bounds__(SC2_THREADS) void scat2_k(
        const float* __restrict__ xm, int N, uint4* __restrict__ xh,
        const int* __restrict__ src, const int* __restrict__ dst, int E, int NQ, int QPB,
        unsigned* __restrict__ gcount, unsigned* __restrict__ ebuf, int C, int nbins,
        uint2* __restrict__ ovf, unsigned* __restrict__ ocur) {
    __shared__ unsigned lcount[MAXBINS];
    __shared__ unsigned lbase[MAXBINS];
    __shared__ unsigned lcur[MAXBINS];
    __shared__ unsigned cstart[MAXBINS];
    __shared__ unsigned wsum[8];
    __shared__ unsigned spk[SC2_CHQ * 4];          // 22.5 KB payload
    __shared__ unsigned short sbin[SC2_CHQ * 4];   // 11.3 KB bin ids
    int tid = threadIdx.x;
    for (int i = tid; i < MAXBINS; i += SC2_THREADS) { lcount[i] = 0u; lcur[i] = 0u; }

    int gid = blockIdx.x * SC2_THREADS + tid;
    int gstride = gridDim.x * SC2_THREADS;
    for (int n = gid; n < N; n += gstride) {
        const float2* r = (const float2*)(xm + (size_t)n * TDIM);
        float2 a = r[0], b = r[1], c = r[2];
        __half2 h0 = __floats2half2_rn(a.x, a.y);
        __half2 h1 = __floats2half2_rn(b.x, b.y);
        __half2 h2 = __floats2half2_rn(c.x, c.y);
        uint4 o;
        o.x = *(unsigned*)&h0; o.y = *(unsigned*)&h1; o.z = *(unsigned*)&h2; o.w = 0u;
        xh[n] = o;
    }
    if (blockIdx.x == 0) {
        for (int e = NQ * 4 + tid; e < E; e += SC2_THREADS) {
            unsigned oc = atomicAdd(ocur, 1u);
            if (oc < OVF_ENT) ovf[oc] = make_uint2((unsigned)src[e], (unsigned)dst[e]);
        }
    }
    __syncthreads();

    int qb = blockIdx.x * QPB;
    int qend = qb + QPB; if (qend > NQ) qend = NQ;
    const int4* s4p = (const int4*)src;
    const int4* d4p = (const int4*)dst;

    // phase 0: block-wide dst histogram
    for (int q = qb + tid; q < qend; q += SC2_THREADS) {
        int4 dv = d4p[q];
        atomicAdd(&lcount[((unsigned)dv.x) >> BINSHIFT], 1u);
        atomicAdd(&lcount[((unsigned)dv.y) >> BINSHIFT], 1u);
        atomicAdd(&lcount[((unsigned)dv.z) >> BINSHIFT], 1u);
        atomicAdd(&lcount[((unsigned)dv.w) >> BINSHIFT], 1u);
    }
    __syncthreads();
    // phase 0b: reserve the block's whole per-bin space once (long runs)
    for (int i = tid; i < nbins; i += SC2_THREADS) {
        unsigned c = lcount[i];
        if (c) lbase[i] = atomicAdd(&gcount[i], c);
    }
    __syncthreads();

    for (int ch = 0; ch < SC2_CHUNKS; ch++) {
        int cb = qb + ch * SC2_CHQ;
        if (cb >= qend) break;
        int ce = cb + SC2_CHQ; if (ce > qend) ce = qend;
        for (int i = tid; i < MAXBINS; i += SC2_THREADS) lcount[i] = 0u;
        __syncthreads();

        unsigned pk[SC2_TQ * 4];
        unsigned wr[SC2_TQ * 4];
#pragma unroll
        for (int i = 0; i < SC2_TQ; i++) {
            int q = cb + tid + i * SC2_THREADS;
            if (q < ce) {
                int4 sv = s4p[q];
                int4 dv = d4p[q];
                {
                    unsigned du = (unsigned)dv.x, b = du >> BINSHIFT;
                    pk[i*4+0] = ((du & (BINSZ-1)) << 18) | (unsigned)sv.x;
                    wr[i*4+0] = (b << 18) | atomicAdd(&lcount[b], 1u);
                }
                {
                    unsigned du = (unsigned)dv.y, b = du >> BINSHIFT;
                    pk[i*4+1] = ((du & (BINSZ-1)) << 18) | (unsigned)sv.y;
                    wr[i*4+1] = (b << 18) | atomicAdd(&lcount[b], 1u);
                }
                {
                    unsigned du = (unsigned)dv.z, b = du >> BINSHIFT;
                    pk[i*4+2] = ((du & (BINSZ-1)) << 18) | (unsigned)sv.z;
                    wr[i*4+2] = (b << 18) | atomicAdd(&lcount[b], 1u);
                }
                {
                    unsigned du = (unsigned)dv.w, b = du >> BINSHIFT;
                    pk[i*4+3] = ((du & (BINSZ-1)) << 18) | (unsigned)sv.w;
                    wr[i*4+3] = (b << 18) | atomicAdd(&lcount[b], 1u);
                }
            } else {
                pk[i*4+0] = 0xFFFFFFFFu; pk[i*4+1] = 0xFFFFFFFFu;
                pk[i*4+2] = 0xFFFFFFFFu; pk[i*4+3] = 0xFFFFFFFFu;
            }
        }
        __syncthreads();

        // chunk-local exclusive scan of lcount (2 bins/thread, wave-shfl)
        unsigned a0 = lcount[2*tid], a1 = lcount[2*tid+1];
        {
            unsigned s = a0 + a1;
            int lane = tid & 63;
#pragma unroll
            for (int off = 1; off < 64; off <<= 1) {
                unsigned t = (unsigned)__shfl_up((int)s, off, 64);
                if (lane >= off) s += t;
            }
            if (lane == 63) wsum[tid >> 6] = s;
            __syncthreads();
            unsigned add = 0; int w = tid >> 6;
#pragma unroll
            for (int ww = 0; ww < 7; ww++) if (ww < w) add += wsum[ww];
            unsigned excl = s + add - (a0 + a1);
            cstart[2*tid] = excl;
            cstart[2*tid+1] = excl + a0;
        }
        __syncthreads();

        // scatter into sorted LDS buffers (payload + bin id)
#pragma unroll
        for (int k = 0; k < SC2_TQ * 4; k++) {
            unsigned p = pk[k];
            if (p != 0xFFFFFFFFu) {
                unsigned b = wr[k] >> 18;
                unsigned r = wr[k] & 0x3FFFFu;
                unsigned li = cstart[b] + r;
                spk[li] = p;
                sbin[li] = (unsigned short)b;
            }
        }
        __syncthreads();

        // coalesced write-out; position recomputed from LDS state; overflow here
        unsigned T = cstart[MAXBINS-1] + lcount[MAXBINS-1];
        for (unsigned j = tid; j < T; j += SC2_THREADS) {
            unsigned p = spk[j];
            unsigned b = (unsigned)sbin[j];
            unsigned pos = lbase[b] + lcur[b] + (j - cstart[b]);
            if (pos < (unsigned)C) {
                ebuf[b * (unsigned)C + pos] = p;
            } else {
                unsigned oc = atomicAdd(ocur, 1u);
                if (oc < OVF_ENT) {
                    ovf[oc] = make_uint2(p & 0x3FFFFu,
                                         (b << BINSHIFT) | (p >> 18));
                }
            }
        }
        // advance per-bin cursors (this thread owns bins 2*tid, 2*tid+1)
        lcur[2*tid]   += a0;
        lcur[2*tid+1] += a1;
        __syncthreads();
    }
}

// v12 accumA: 2 blocks/bin, disjoint half-ranges, partials to pbuf.
__global__ __launch_bounds__(512) void accum_a_k(
        const uint4* __restrict__ xh,
        const unsigned* __restrict__ ebuf, const unsigned* __restrict__ gcount, int C,
        const unsigned* __restrict__ ocur, const uint2* __restrict__ ovf,
        float* __restrict__ pbuf, int nbins) {
    __shared__ unsigned srt[SRT_HALF];
    __shared__ unsigned cnt[BINSZ];
    __shared__ unsigned cstart[BINSZ];
    __shared__ unsigned wsum[4];
    __shared__ unsigned ovl[256];
    __shared__ unsigned ovn;
    float (*part)[BINSZ][TDIM] = (float(*)[BINSZ][TDIM])srt;
    int tid = threadIdx.x;
    int bh = blockIdx.x;
    int bin = bh >> 1;
    unsigned half = (unsigned)(bh & 1);
    if (tid < BINSZ) cnt[tid] = 0u;
    if (tid == 0) ovn = 0u;
    __syncthreads();

    unsigned gc = gcount[bin];
    unsigned m = gc < (unsigned)C ? gc : (unsigned)C;
    unsigned lo = half ? (m >> 1) : 0u;
    unsigned hi = half ? m : (m >> 1);
    unsigned e0 = (unsigned)bin * (unsigned)C;

    unsigned ed_[AH_EPT];
    unsigned rk_[AH_EPT];
#pragma unroll
    for (int k = 0; k < AH_EPT; k++) {
        ed_[k] = 0xFFFFFFFFu;
        unsigned i = lo + (unsigned)tid + (unsigned)k * 512u;
        if (i < hi) {
            unsigned v = __builtin_nontemporal_load(ebuf + e0 + i);
            ed_[k] = v;
            rk_[k] = atomicAdd(&cnt[v >> 18], 1u);
        }
    }
    if (half == 0u) {
        unsigned novf = *ocur;
        if (novf > OVF_ENT) novf = OVF_ENT;
        for (unsigned i = tid; i < novf; i += 512u) {
            uint2 e = ovf[i];
            if ((e.y >> BINSHIFT) == (unsigned)bin) {
                unsigned u = atomicAdd(&ovn, 1u);
                if (u < 256u) ovl[u] = ((e.y & (BINSZ-1)) << 18) | e.x;
            }
        }
    }
    __syncthreads();

    {
        unsigned v = (tid < BINSZ) ? cnt[tid] : 0u;
        int lane = tid & 63;
#pragma unroll
        for (int off = 1; off < 64; off <<= 1) {
            unsigned t = (unsigned)__shfl_up((int)v, off, 64);
            if (lane >= off) v += t;
        }
        if (tid < BINSZ && lane == 63) wsum[tid >> 6] = v;
        __syncthreads();
        if (tid < BINSZ) {
            unsigned add = 0;
            int w = tid >> 6;
#pragma unroll
            for (int ww = 0; ww < 3; ww++) if (ww < w) add += wsum[ww];
            cstart[tid] = v + add - cnt[tid];
        }
        __syncthreads();
    }

#pragma unroll
    for (int k = 0; k < AH_EPT; k++) {
        unsigned v = ed_[k];
        if (v != 0xFFFFFFFFu) srt[cstart[v >> 18] + rk_[k]] = v & 0x3FFFFu;
    }
    __syncthreads();

    int node = tid & (BINSZ - 1);
    int role = tid >> 8;
    float s0 = 0.f, s1 = 0.f, s2 = 0.f, s3 = 0.f, s4 = 0.f, s5 = 0.f;
    {
        unsigned c = cnt[node];
        unsigned b0 = cstart[node];
        unsigned h2 = c >> 1;
        unsigned j  = role ? h2 : 0u;
        unsigned je = role ? c : h2;
        for (; j + 8 <= je; j += 8) {
            unsigned i0 = srt[b0 + j],     i1 = srt[b0 + j + 1];
            unsigned i2 = srt[b0 + j + 2], i3 = srt[b0 + j + 3];
            unsigned i4 = srt[b0 + j + 4], i5 = srt[b0 + j + 5];
            unsigned i6 = srt[b0 + j + 6], i7 = srt[b0 + j + 7];
            uint4 r0 = xh[i0], r1 = xh[i1], r2 = xh[i2], r3 = xh[i3];
            uint4 r4 = xh[i4], r5 = xh[i5], r6 = xh[i6], r7 = xh[i7];
            add_row4(r0, s0, s1, s2, s3, s4, s5);
            add_row4(r1, s0, s1, s2, s3, s4, s5);
            add_row4(r2, s0, s1, s2, s3, s4, s5);
            add_row4(r3, s0, s1, s2, s3, s4, s5);
            add_row4(r4, s0, s1, s2, s3, s4, s5);
            add_row4(r5, s0, s1, s2, s3, s4, s5);
            add_row4(r6, s0, s1, s2, s3, s4, s5);
            add_row4(r7, s0, s1, s2, s3, s4, s5);
        }
        for (; j + 2 <= je; j += 2) {
            unsigned ia = srt[b0 + j], ib = srt[b0 + j + 1];
            uint4 ra = xh[ia], rb = xh[ib];
            add_row4(ra, s0, s1, s2, s3, s4, s5);
            add_row4(rb, s0, s1, s2, s3, s4, s5);
        }
        if (j < je) {
            uint4 ra = xh[srt[b0 + j]];
            add_row4(ra, s0, s1, s2, s3, s4, s5);
        }
        if (role == 0) {
            unsigned no = ovn < 256u ? ovn : 256u;
            for (unsigned q = 0; q < no; q++) {
                unsigned o = ovl[q];
                if ((int)(o >> 18) == node) {
                    uint4 rr = xh[o & 0x3FFFFu];
                    add_row4(rr, s0, s1, s2, s3, s4, s5);
                }
            }
        }
    }
    __syncthreads();
    part[role][node][0] = s0; part[role][node][1] = s1; part[role][node][2] = s2;
    part[role][node][3] = s3; part[role][node][4] = s4; part[role][node][5] = s5;
    __syncthreads();

    float* pb = pbuf + (size_t)bh * PB_NODE;
    for (int j = tid; j < PB_NODE; j += 512) {
        int nd = j / TDIM, d = j - nd * TDIM;
        pb[j] = part[0][nd][d] + part[1][nd][d];
    }
}

// v12 accumB: fully-parallel fused MLP over nodes.
__global__ __launch_bounds__(256) void accum_b_k(
        const float* __restrict__ xm, const float* __restrict__ pbuf,
        const float* __restrict__ H, const float* __restrict__ W,
        float* __restrict__ facc, int N) {
    __shared__ float sH[LDIM * TDIM * MDIM];
    __shared__ float sW[LDIM];
    __shared__ float sred[4][MDIM];
    int tid = threadIdx.x;
    for (int i = tid; i < LDIM * TDIM * MDIM; i += 256) sH[i] = H[i];
    if (tid < LDIM) sW[tid] = W[tid];
    __syncthreads();

    int n = blockIdx.x * 256 + tid;
    float fs[MDIM];
#pragma unroll
    for (int mm = 0; mm < MDIM; mm++) fs[mm] = 0.f;

    if (n < N) {
        int bin = n >> BINSHIFT;
        int node = n & (BINSZ - 1);
        const float* p0 = pbuf + (size_t)(bin * 2 + 0) * PB_NODE + node * TDIM;
        const float* p1 = pbuf + (size_t)(bin * 2 + 1) * PB_NODE + node * TDIM;
        const float2* xr = (const float2*)(xm + (size_t)n * TDIM);
        float2 x0 = xr[0], x1 = xr[1], x2 = xr[2];
        float v[TDIM];
        v[0] = x0.x + p0[0] + p1[0];
        v[1] = x0.y + p0[1] + p1[1];
        v[2] = x1.x + p0[2] + p1[2];
        v[3] = x1.y + p0[3] + p1[3];
        v[4] = x2.x + p0[4] + p1[4];
        v[5] = x2.y + p0[5] + p1[5];

#pragma unroll
        for (int l = 0; l < LDIM; l++) {
            float z[MDIM];
#pragma unroll
            for (int mm = 0; mm < MDIM; mm++) {
                float a2 = 0.f;
#pragma unroll
                for (int t = 0; t < TDIM; t++) a2 += v[t] * sH[(l * TDIM + t) * MDIM + mm];
                z[mm] = a2;
            }
            float wl = sW[l];
            float mx = -1e30f;
#pragma unroll
            for (int mm = 0; mm < MDIM; mm++) {
                float sg = wl / (1.f + __expf(-z[mm]));
                z[mm] = sg;
                mx = fmaxf(mx, sg);
            }
            float se = 0.f;
#pragma unroll
            for (int mm = 0; mm < MDIM; mm++) {
                float e = __expf(z[mm] - mx);
                z[mm] = e;
                se += e;
            }
            float inv = 1.f / se;
#pragma unroll
            for (int mm = 0; mm < MDIM; mm++) fs[mm] += z[mm] * inv;
        }
    }

#pragma unroll
    for (int mm = 0; mm < MDIM; mm++) {
        float v = fs[mm];
#pragma unroll
        for (int off = 32; off > 0; off >>= 1) v += __shfl_down(v, off, 64);
        fs[mm] = v;
    }
    int wave = tid >> 6, lane = tid & 63;
    if (lane == 0) {
#pragma unroll
        for (int mm = 0; mm < MDIM; mm++) sred[wave][mm] = fs[mm];
    }
    __syncthreads();
    if (tid < MDIM) {
        float s = 0.f;
#pragma unroll
        for (int w = 0; w < 4; w++) s += sred[w][tid];
        atomicAdd(facc + tid, s);
    }
}

// v11 accum2 (fallback when pbuf doesn't fit in workspace)
__global__ __launch_bounds__(AC_BLOCK) void accum2_k(
        const float* __restrict__ xm, const uint4* __restrict__ xh,
        const unsigned* __restrict__ ebuf, const unsigned* __restrict__ gcount, int C,
        const unsigned* __restrict__ ocur, const uint2* __restrict__ ovf,
        const float* __restrict__ H, const float* __restrict__ W,
        float* __restrict__ facc, int N) {
    __shared__ unsigned srt[AC_CAP];
    __shared__ unsigned cnt[BINSZ];
    __shared__ unsigned cstart[BINSZ];
    __shared__ unsigned wsum[8];
    __shared__ unsigned ovl[256];
    __shared__ unsigned ovn;
    __shared__ float sH[LDIM * TDIM * MDIM];
    __shared__ float sW[LDIM];
    __shared__ float sred[AC_BLOCK / 64][MDIM];
    float (*part)[BINSZ][TDIM] = (float(*)[BINSZ][TDIM])srt;
    int tid = threadIdx.x;
    int bin = blockIdx.x;
    for (int i = tid; i < LDIM * TDIM * MDIM; i += AC_BLOCK) sH[i] = H[i];
    if (tid < LDIM) sW[tid] = W[tid];
    if (tid < BINSZ) cnt[tid] = 0u;
    if (tid == 0) ovn = 0u;
    __syncthreads();

    unsigned gc = gcount[bin];
    unsigned m = gc < (unsigned)C ? gc : (unsigned)C;
    unsigned e0 = (unsigned)bin * (unsigned)C;
    int nbase = bin << BINSHIFT;

    unsigned ed_[AC_EPT];
    unsigned rk_[AC_EPT];
#pragma unroll
    for (int k = 0; k < AC_EPT; k++) {
        unsigned i = (unsigned)tid + (unsigned)k * AC_BLOCK;
        if (i < m) {
            unsigned v = __builtin_nontemporal_load(ebuf + e0 + i);
            ed_[k] = v;
            rk_[k] = atomicAdd(&cnt[v >> 18], 1u);
        }
    }
    {
        unsigned novf = *ocur;
        if (novf > OVF_ENT) novf = OVF_ENT;
        for (unsigned i = tid; i < novf; i += AC_BLOCK) {
            uint2 e = ovf[i];
            if ((e.y >> BINSHIFT) == (unsigned)bin) {
                unsigned u = atomicAdd(&ovn, 1u);
                if (u < 256u) ovl[u] = ((e.y & (BINSZ-1)) << 18) | e.x;
            }
        }
    }
    __syncthreads();

    {
        unsigned v = (tid < BINSZ) ? cnt[tid] : 0u;
        int lane = tid & 63;
#pragma unroll
        for (int off = 1; off < 64; off <<= 1) {
            unsigned t = (unsigned)__shfl_up((int)v, off, 64);
            if (lane >= off) v += t;
        }
        if (tid < BINSZ && lane == 63) wsum[tid >> 6] = v;
        __syncthreads();
        if (tid < BINSZ) {
            unsigned add = 0;
            int w = tid >> 6;
#pragma unroll
            for (int ww = 0; ww < 3; ww++) if (ww < w) add += wsum[ww];
            cstart[tid] = v + add - cnt[tid];
        }
        __syncthreads();
    }

#pragma unroll
    for (int k = 0; k < AC_EPT; k++) {
        unsigned i = (unsigned)tid + (unsigned)k * AC_BLOCK;
        if (i < m) {
            unsigned v = ed_[k];
            srt[cstart[v >> 18] + rk_[k]] = v & 0x3FFFFu;
        }
    }
    __syncthreads();

    int node = tid & (BINSZ - 1);
    int role = tid >> 8;
    int n = nbase + node;
    float s0 = 0.f, s1 = 0.f, s2 = 0.f, s3 = 0.f, s4 = 0.f, s5 = 0.f;
    if (n < N) {
        unsigned c = cnt[node];
        unsigned b0 = cstart[node];
        unsigned h = c >> 1;
        unsigned j  = role ? h : 0u;
        unsigned je = role ? c : h;
        for (; j + 8 <= je; j += 8) {
            unsigned i0 = srt[b0 + j],     i1 = srt[b0 + j + 1];
            unsigned i2 = srt[b0 + j + 2], i3 = srt[b0 + j + 3];
            unsigned i4 = srt[b0 + j + 4], i5 = srt[b0 + j + 5];
            unsigned i6 = srt[b0 + j + 6], i7 = srt[b0 + j + 7];
            uint4 r0 = xh[i0], r1 = xh[i1], r2 = xh[i2], r3 = xh[i3];
            uint4 r4 = xh[i4], r5 = xh[i5], r6 = xh[i6], r7 = xh[i7];
            add_row4(r0, s0, s1, s2, s3, s4, s5);
            add_row4(r1, s0, s1, s2, s3, s4, s5);
            add_row4(r2, s0, s1, s2, s3, s4, s5);
            add_row4(r3, s0, s1, s2, s3, s4, s5);
            add_row4(r4, s0, s1, s2, s3, s4, s5);
            add_row4(r5, s0, s1, s2, s3, s4, s5);
            add_row4(r6, s0, s1, s2, s3, s4, s5);
            add_row4(r7, s0, s1, s2, s3, s4, s5);
        }
        for (; j + 2 <= je; j += 2) {
            unsigned ia = srt[b0 + j], ib = srt[b0 + j + 1];
            uint4 ra = xh[ia], rb = xh[ib];
            add_row4(ra, s0, s1, s2, s3, s4, s5);
            add_row4(rb, s0, s1, s2, s3, s4, s5);
        }
        if (j < je) {
            uint4 ra = xh[srt[b0 + j]];
            add_row4(ra, s0, s1, s2, s3, s4, s5);
        }
        if (role == 0) {
            unsigned no = ovn < 256u ? ovn : 256u;
            for (unsigned q = 0; q < no; q++) {
                unsigned o = ovl[q];
                if ((int)(o >> 18) == node) {
                    uint4 rr = xh[o & 0x3FFFFu];
                    add_row4(rr, s0, s1, s2, s3, s4, s5);
                }
            }
        }
    }
    __syncthreads();
    part[role][node][0] = s0; part[role][node][1] = s1; part[role][node][2] = s2;
    part[role][node][3] = s3; part[role][node][4] = s4; part[role][node][5] = s5;
    __syncthreads();

    float fs[MDIM];
#pragma unroll
    for (int mm = 0; mm < MDIM; mm++) fs[mm] = 0.f;

    if (n < N) {
        float v[TDIM];
        const float2* xr = (const float2*)(xm + (size_t)n * TDIM);
        float2 x0 = xr[0], x1 = xr[1], x2 = xr[2];
        v[0] = x0.x + part[0][node][0] + part[1][node][0];
        v[1] = x0.y + part[0][node][1] + part[1][node][1];
        v[2] = x1.x + part[0][node][2] + part[1][node][2];
        v[3] = x1.y + part[0][node][3] + part[1][node][3];
        v[4] = x2.x + part[0][node][4] + part[1][node][4];
        v[5] = x2.y + part[0][node][5] + part[1][node][5];

        int lb = role << 1;
#pragma unroll
        for (int li = 0; li < 2; li++) {
            int l = lb + li;
            float z[MDIM];
#pragma unroll
            for (int mm = 0; mm < MDIM; mm++) {
                float a2 = 0.f;
#pragma unroll
                for (int t = 0; t < TDIM; t++) a2 += v[t] * sH[(l * TDIM + t) * MDIM + mm];
                z[mm] = a2;
            }
            float wl = sW[l];
            float mx = -1e30f;
#pragma unroll
            for (int mm = 0; mm < MDIM; mm++) {
                float sg = wl / (1.f + __expf(-z[mm]));
                z[mm] = sg;
                mx = fmaxf(mx, sg);
            }
            float se = 0.f;
#pragma unroll
            for (int mm = 0; mm < MDIM; mm++) {
                float e = __expf(z[mm] - mx);
                z[mm] = e;
                se += e;
            }
            float inv = 1.f / se;
#pragma unroll
            for (int mm = 0; mm < MDIM; mm++) fs[mm] += z[mm] * inv;
        }
    }

#pragma unroll
    for (int mm = 0; mm < MDIM; mm++) {
        float v = fs[mm];
#pragma unroll
        for (int off = 32; off > 0; off >>= 1) v += __shfl_down(v, off, 64);
        fs[mm] = v;
    }
    int wave = tid >> 6, lane = tid & 63;
    if (lane == 0) {
#pragma unroll
        for (int mm = 0; mm < MDIM; mm++) sred[wave][mm] = fs[mm];
    }
    __syncthreads();
    if (tid < MDIM) {
        float s = 0.f;
#pragma unroll
        for (int w = 0; w < AC_BLOCK / 64; w++) s += sred[w][tid];
        atomicAdd(facc + tid, s);
    }
}

// ================= TIER 2: legacy hist/scan path =================

__global__ __launch_bounds__(256) void prep_k(const float* __restrict__ xm, int N,
                                              uint4* __restrict__ xh,
                                              const int* __restrict__ dst, int E,
                                              unsigned* __restrict__ hist, int nbins) {
    __shared__ unsigned lh[MAXBINS];
    for (int i = threadIdx.x; i < MAXBINS; i += blockDim.x) lh[i] = 0u;
    __syncthreads();
    int gid = blockIdx.x * blockDim.x + threadIdx.x;
    int gstride = gridDim.x * blockDim.x;
    for (int n = gid; n < N; n += gstride) {
        const float2* r = (const float2*)(xm + (size_t)n * TDIM);
        float2 a = r[0], b = r[1], c = r[2];
        __half2 h0 = __floats2half2_rn(a.x, a.y);
        __half2 h1 = __floats2half2_rn(b.x, b.y);
        __half2 h2 = __floats2half2_rn(c.x, c.y);
        uint4 o;
        o.x = *(unsigned*)&h0; o.y = *(unsigned*)&h1; o.z = *(unsigned*)&h2; o.w = 0u;
        xh[n] = o;
    }
    int e4 = E >> 2;
    const int4* d4p = (const int4*)dst;
    for (int i = gid; i < e4; i += gstride) {
        int4 d = d4p[i];
        atomicAdd(&lh[((unsigned)d.x) >> BINSHIFT], 1u);
        atomicAdd(&lh[((unsigned)d.y) >> BINSHIFT], 1u);
        atomicAdd(&lh[((unsigned)d.z) >> BINSHIFT], 1u);
        atomicAdd(&lh[((unsigned)d.w) >> BINSHIFT], 1u);
    }
    for (int e = (e4 << 2) + gid; e < E; e += gstride)
        atomicAdd(&lh[((unsigned)dst[e]) >> BINSHIFT], 1u);
    __syncthreads();
    for (int i = threadIdx.x; i < nbins; i += blockDim.x)
        if (lh[i]) atomicAdd(&hist[i], lh[i]);
}

__global__ __launch_bounds__(MAXBINS) void scan_k(const unsigned* __restrict__ hist,
                                                  unsigned* __restrict__ offsets,
                                                  unsigned* __restrict__ gfill, int nbins) {
    __shared__ unsigned buf[2][MAXBINS];
    int t = threadIdx.x;
    buf[0][t] = (t < nbins) ? hist[t] : 0u;
    __syncthreads();
    int cur = 0;
    for (int off = 1; off < MAXBINS; off <<= 1) {
        unsigned v = buf[cur][t];
        if (t >= off) v += buf[cur][t - off];
        buf[cur ^ 1][t] = v;
        __syncthreads();
        cur ^= 1;
    }
    if (t < nbins) {
        unsigned ex = t ? buf[cur][t - 1] : 0u;
        offsets[t] = ex;
        gfill[t] = ex;
    }
    if (t == 0) offsets[nbins] = buf[cur][nbins - 1];
}

__global__ __launch_bounds__(SC_BLOCK) void scatter_k(const int* __restrict__ src,
                                                      const int* __restrict__ dst, int E,
                                                      unsigned* __restrict__ gfill,
                                                      unsigned* __restrict__ ebuf, int nbins) {
    __shared__ unsigned lcount[MAXBINS];
    __shared__ unsigned lbase[MAXBINS];
    for (int i = threadIdx.x; i < MAXBINS; i += SC_BLOCK) lcount[i] = 0u;
    __syncthreads();
    int base = blockIdx.x * SC_EPB + threadIdx.x * SC_EPT;
    int s[SC_EPT], d[SC_EPT];
    unsigned rk[SC_EPT];
#pragma unroll
    for (int q = 0; q < SC_EPT / 4; q++) {
        int e = base + q * 4;
        if (e + 3 < E) {
            int4 s4 = *(const int4*)(src + e);
            int4 d4 = *(const int4*)(dst + e);
            s[q*4+0] = s4.x; s[q*4+1] = s4.y; s[q*4+2] = s4.z; s[q*4+3] = s4.w;
            d[q*4+0] = d4.x; d[q*4+1] = d4.y; d[q*4+2] = d4.z; d[q*4+3] = d4.w;
        } else {
#pragma unroll
            for (int k = 0; k < 4; k++) {
                int ee = e + k;
                s[q*4+k] = (ee < E) ? src[ee] : -1;
                d[q*4+k] = (ee < E) ? dst[ee] : 0;
            }
        }
    }
#pragma unroll
    for (int k = 0; k < SC_EPT; k++)
        if (s[k] >= 0) rk[k] = atomicAdd(&lcount[((unsigned)d[k]) >> BINSHIFT], 1u);
    __syncthreads();
    for (int i = threadIdx.x; i < nbins; i += SC_BLOCK) {
        unsigned c = lcount[i];
        if (c) lbase[i] = atomicAdd(&gfill[i], c);
    }
    __syncthreads();
#pragma unroll
    for (int k = 0; k < SC_EPT; k++) {
        if (s[k] >= 0) {
            unsigned du = (unsigned)d[k];
            unsigned b = du >> BINSHIFT;
            unsigned pack = ((du & (BINSZ - 1)) << 18) | (unsigned)s[k];
            ebuf[lbase[b] + rk[k]] = pack;
        }
    }
}

__global__ __launch_bounds__(AC_BLOCK) void accum_node_k(
        const float* __restrict__ xm, const uint4* __restrict__ xh,
        const unsigned* __restrict__ ebuf, const unsigned* __restrict__ offsets,
        const float* __restrict__ H, const float* __restrict__ W,
        float* __restrict__ facc, int N) {
    __shared__ unsigned srt[AC_CAP];
    __shared__ unsigned cnt[BINSZ];
    __shared__ unsigned tmp[BINSZ];
    __shared__ unsigned cstart[BINSZ];
    __shared__ float sH[LDIM * TDIM * MDIM];
    __shared__ float sW[LDIM];
    __shared__ float sred[AC_BLOCK / 64][MDIM];
    int tid = threadIdx.x;
    int bin = blockIdx.x;
    for (int i = tid; i < LDIM * TDIM * MDIM; i += AC_BLOCK) sH[i] = H[i];
    if (tid < LDIM) sW[tid] = W[tid];
    if (tid < BINSZ) cnt[tid] = 0u;
    __syncthreads();

    unsigned e0 = offsets[bin], e1 = offsets[bin + 1];
    unsigned total = e1 - e0;
    unsigned m = total < AC_CAP ? total : AC_CAP;
    int nbase = bin << BINSHIFT;

    unsigned ed_[AC_EPT];
    unsigned rk_[AC_EPT];
#pragma unroll
    for (int k = 0; k < AC_EPT; k++) {
        unsigned idx = e0 + (unsigned)tid + (unsigned)k * AC_BLOCK;
        if (idx < e0 + m) {
            unsigned v = ebuf[idx];
            ed_[k] = v;
            rk_[k] = atomicAdd(&cnt[v >> 18], 1u);
        }
    }
    __syncthreads();

    if (tid < BINSZ) tmp[tid] = cnt[tid];
    __syncthreads();
    for (int off = 1; off < BINSZ; off <<= 1) {
        unsigned v = 0;
        if (tid < BINSZ) { v = tmp[tid]; if (tid >= off) v += tmp[tid - off]; }
        __syncthreads();
        if (tid < BINSZ) tmp[tid] = v;
        __syncthreads();
    }
    if (tid < BINSZ) cstart[tid] = tmp[tid] - cnt[tid];
    __syncthreads();

#pragma unroll
    for (int k = 0; k < AC_EPT; k++) {
        unsigned idx = e0 + (unsigned)tid + (unsigned)k * AC_BLOCK;
        if (idx < e0 + m) {
            unsigned v = ed_[k];
            srt[cstart[v >> 18] + rk_[k]] = v & 0x3FFFFu;
        }
    }
    __syncthreads();

    float fs[MDIM];
#pragma unroll
    for (int mm = 0; mm < MDIM; mm++) fs[mm] = 0.f;

    int n = nbase + tid;
    if (tid < BINSZ && n < N) {
        float s0 = 0.f, s1 = 0.f, s2 = 0.f, s3 = 0.f, s4 = 0.f, s5 = 0.f;
        unsigned c = cnt[tid];
        unsigned b0 = cstart[tid];
        unsigned j = 0;
        for (; j + 2 <= c; j += 2) {
            unsigned sa = srt[b0 + j], sb = srt[b0 + j + 1];
            uint4 ra = xh[sa];
            uint4 rb = xh[sb];
            add_row4(ra, s0, s1, s2, s3, s4, s5);
            add_row4(rb, s0, s1, s2, s3, s4, s5);
        }
        if (j < c) {
            uint4 ra = xh[srt[b0 + j]];
            add_row4(ra, s0, s1, s2, s3, s4, s5);
        }
        for (unsigned idx = e0 + m; idx < e1; idx++) {
            unsigned v = ebuf[idx];
            if ((int)(v >> 18) == tid) {
                uint4 ra = xh[v & 0x3FFFFu];
                add_row4(ra, s0, s1, s2, s3, s4, s5);
            }
        }

        float v[TDIM];
        const float2* xr = (const float2*)(xm + (size_t)n * TDIM);
        float2 x0 = xr[0], x1 = xr[1], x2 = xr[2];
        v[0] = x0.x + s0; v[1] = x0.y + s1;
        v[2] = x1.x + s2; v[3] = x1.y + s3;
        v[4] = x2.x + s4; v[5] = x2.y + s5;

#pragma unroll
        for (int l = 0; l < LDIM; l++) {
            float z[MDIM];
#pragma unroll
            for (int mm = 0; mm < MDIM; mm++) {
                float a2 = 0.f;
#pragma unroll
                for (int t = 0; t < TDIM; t++) a2 += v[t] * sH[(l * TDIM + t) * MDIM + mm];
                z[mm] = a2;
            }
            float wl = sW[l];
            float mx = -1e30f;
#pragma unroll
            for (int mm = 0; mm < MDIM; mm++) {
                float sg = wl / (1.f + __expf(-z[mm]));
                z[mm] = sg;
                mx = fmaxf(mx, sg);
            }
            float se = 0.f;
#pragma unroll
            for (int mm = 0; mm < MDIM; mm++) {
                float e = __expf(z[mm] - mx);
                z[mm] = e;
                se += e;
            }
            float inv = 1.f / se;
#pragma unroll
            for (int mm = 0; mm < MDIM; mm++) fs[mm] += z[mm] * inv;
        }
    }

#pragma unroll
    for (int mm = 0; mm < MDIM; mm++) {
        float v = fs[mm];
#pragma unroll
        for (int off = 32; off > 0; off >>= 1) v += __shfl_down(v, off, 64);
        fs[mm] = v;
    }
    int wave = tid >> 6, lane = tid & 63;
    if (lane == 0) {
#pragma unroll
        for (int mm = 0; mm < MDIM; mm++) sred[wave][mm] = fs[mm];
    }
    __syncthreads();
    if (tid < MDIM) {
        float s = 0.f;
#pragma unroll
        for (int w = 0; w < AC_BLOCK / 64; w++) s += sred[w][tid];
        atomicAdd(facc + tid, s);
    }
}

// ---------------- final tiny perceptron ----------------
__global__ void finalize_k(const float* __restrict__ facc,
                           const float* __restrict__ xg,
                           const float* __restrict__ gW,
                           const float* __restrict__ gb,
                           const float* __restrict__ mW,
                           const float* __restrict__ mb,
                           float* __restrict__ out) {
    if (threadIdx.x == 0 && blockIdx.x == 0) {
        float merged[MDIM + GLOD];
#pragma unroll
        for (int m = 0; m < MDIM; m++) merged[m] = facc[m];
        for (int j = 0; j < GLOD; j++) {
            float a = gb[j];
            for (int i = 0; i < GIND; i++) a += xg[i] * gW[j * GIND + i];
            merged[MDIM + j] = 1.f / (1.f + __expf(-a));
        }
        float lg[3];
        float mx = -1e30f;
        for (int k = 0; k < 3; k++) {
            float a = mb[k];
            for (int j = 0; j < MDIM + GLOD; j++) a += merged[j] * mW[k * (MDIM + GLOD) + j];
            lg[k] = a;
            mx = fmaxf(mx, a);
        }
        float se = 0.f;
        for (int k = 0; k < 3; k++) { lg[k] = __expf(lg[k] - mx); se += lg[k]; }
        float inv = 1.f / se;
        for (int k = 0; k < 3; k++) out[k] = lg[k] * inv;
    }
}

// ---------------- TIER 3 fallback: global-atomic path ----------------
__global__ void fb_zero_k(float* __restrict__ ws, int n) {
    int i = blockIdx.x * blockDim.x + threadIdx.x;
    if (i < n) ws[i] = 0.f;
}

__global__ void fb_edge_scatter_k(const float* __restrict__ xm,
                                  const int* __restrict__ src,
                                  const int* __restrict__ dst,
                                  float* __restrict__ neigh, int E) {
    int e = blockIdx.x * blockDim.x + threadIdx.x;
    if (e >= E) return;
    int s = src[e], d = dst[e];
    const float2* r = (const float2*)(xm + (size_t)s * TDIM);
    float2 a = r[0], b = r[1], c = r[2];
    float* o = neigh + (size_t)d * TDIM;
    atomicAdd(o + 0, a.x); atomicAdd(o + 1, a.y);
    atomicAdd(o + 2, b.x); atomicAdd(o + 3, b.y);
    atomicAdd(o + 4, c.x); atomicAdd(o + 5, c.y);
}

__global__ __launch_bounds__(256) void fb_node_k(
        const float* __restrict__ xm, const float* __restrict__ neigh,
        const float* __restrict__ H, const float* __restrict__ W,
        float* __restrict__ facc, int N) {
    __shared__ float sH[LDIM * TDIM * MDIM];
    __shared__ float sW[LDIM];
    __shared__ float sred[4][MDIM];
    int tid = threadIdx.x;
    for (int i = tid; i < LDIM * TDIM * MDIM; i += blockDim.x) sH[i] = H[i];
    if (tid < LDIM) sW[tid] = W[tid];
    __syncthreads();
    float fs[MDIM];
#pragma unroll
    for (int m = 0; m < MDIM; m++) fs[m] = 0.f;
    for (int n = blockIdx.x * blockDim.x + tid; n < N; n += gridDim.x * blockDim.x) {
        float v[TDIM];
        const float2* xr = (const float2*)(xm + (size_t)n * TDIM);
        const float2* nr = (const float2*)(neigh + (size_t)n * TDIM);
#pragma unroll
        for (int t2 = 0; t2 < 3; t2++) {
            float2 a = xr[t2], b = nr[t2];
            v[2 * t2 + 0] = a.x + b.x;
            v[2 * t2 + 1] = a.y + b.y;
        }
#pragma unroll
        for (int l = 0; l < LDIM; l++) {
            float z[MDIM];
#pragma unroll
            for (int m = 0; m < MDIM; m++) {
                float a2 = 0.f;
#pragma unroll
                for (int t = 0; t < TDIM; t++) a2 += v[t] * sH[(l * TDIM + t) * MDIM + m];
                z[m] = a2;
            }
            float wl = sW[l], mx = -1e30f;
#pragma unroll
            for (int m = 0; m < MDIM; m++) { float sg = wl / (1.f + __expf(-z[m])); z[m] = sg; mx = fmaxf(mx, sg); }
            float se = 0.f;
#pragma unroll
            for (int m = 0; m < MDIM; m++) { float e = __expf(z[m] - mx); z[m] = e; se += e; }
            float inv = 1.f / se;
#pragma unroll
            for (int m = 0; m < MDIM; m++) fs[m] += z[m] * inv;
        }
    }
#pragma unroll
    for (int m = 0; m < MDIM; m++) {
        float v = fs[m];
#pragma unroll
        for (int off = 32; off > 0; off >>= 1) v += __shfl_down(v, off, 64);
        fs[m] = v;
    }
    int wave = tid >> 6, lane = tid & 63;
    if (lane == 0) {
#pragma unroll
        for (int m = 0; m < MDIM; m++) sred[wave][m] = fs[m];
    }
    __syncthreads();
    if (tid < MDIM) {
        float s = sred[0][tid] + sred[1][tid] + sred[2][tid] + sred[3][tid];
        atomicAdd(facc + tid, s);
    }
}

extern "C" void kernel_launch(void* const* d_in, const int* in_sizes, int n_in,
                              void* d_out, int out_size, void* d_ws, size_t ws_size,
                              hipStream_t stream) {
    const float* xm  = (const float*)d_in[0];
    const float* xg  = (const float*)d_in[1];
    const int*   src = (const int*)d_in[2];
    const int*   dst = (const int*)d_in[3];
    const float* H   = (const float*)d_in[4];
    const float* W   = (const float*)d_in[5];
    const float* gW  = (const float*)d_in[6];
    const float* gb  = (const float*)d_in[7];
    const float* mW  = (const float*)d_in[8];
    const float* mb  = (const float*)d_in[9];
    float* out = (float*)d_out;

    int N = in_sizes[0] / TDIM;
    int E = in_sizes[2];
    int nbins = (N + BINSZ - 1) >> BINSHIFT;
    size_t ws_words = ws_size / 4;
    size_t xh_words = (size_t)N * 4;
    size_t pbuf_words = (size_t)nbins * 2 * PB_NODE;

    double mu = (double)E / nbins;
    long Cmin = (long)(mu + 4.0 * sqrt(mu) + 32.0);
    int NQ = E >> 2;
    int QPB = (NQ + SC2_BLOCKS - 1) / SC2_BLOCKS;
    bool qpb_ok = QPB <= SC2_CHUNKS * SC2_CHQ;

    // ---- tier 1a: split accum (needs pbuf) ----
    long fixed_s = (long)(xh_words + META2 + (size_t)OVF_ENT * 2 + pbuf_words);
    long avail_s = (long)ws_words - fixed_s;
    long Cs = avail_s > 0 ? (avail_s / nbins) & ~3L : 0;
    if (Cs > AC_CAP) Cs = AC_CAP;
    bool ok1s = (Cs >= Cmin) && nbins <= MAXBINS && N <= (1 << 18) && qpb_ok;

    // ---- tier 1b: v11 single-kernel accum ----
    long fixed = (long)(xh_words + META2 + (size_t)OVF_ENT * 2);
    long avail = (long)ws_words - fixed;
    long C = avail > 0 ? (avail / nbins) & ~3L : 0;
    if (C > AC_CAP) C = AC_CAP;
    bool ok1 = (C >= Cmin) && nbins <= MAXBINS && N <= (1 << 18) && qpb_ok;

    // ---- tier 2: legacy hist/scan ----
    size_t meta_words2 = MAXBINS + (MAXBINS + 1) + MAXBINS + 16;
    size_t need2 = (xh_words + (size_t)E + meta_words2) * 4;
    bool ok2 = ws_size >= need2 && nbins <= MAXBINS && N <= (1 << 18);

    if (ok1s) {
        uint4*    xh     = (uint4*)d_ws;
        unsigned* ebuf   = (unsigned*)d_ws + xh_words;
        unsigned* gcount = ebuf + (size_t)nbins * Cs;
        unsigned* ocur   = gcount + MAXBINS;
        float*    facc   = (float*)(ocur + 16);
        uint2*    ovf    = (uint2*)(gcount + META2);
        float*    pbuf   = (float*)(gcount + META2 + (size_t)OVF_ENT * 2);

        zero32_k<<<(META2 + 255) / 256, 256, 0, stream>>>(gcount, META2);
        scat2_k<<<SC2_BLOCKS, SC2_THREADS, 0, stream>>>(xm, N, xh, src, dst, E, NQ, QPB,
                                                        gcount, ebuf, (int)Cs, nbins, ovf, ocur);
        accum_a_k<<<nbins * 2, 512, 0, stream>>>(xh, ebuf, gcount, (int)Cs, ocur, ovf,
                                                 pbuf, nbins);
        accum_b_k<<<(N + 255) / 256, 256, 0, stream>>>(xm, pbuf, H, W, facc, N);
        finalize_k<<<1, 64, 0, stream>>>(facc, xg, gW, gb, mW, mb, out);
    } else if (ok1) {
        uint4*    xh     = (uint4*)d_ws;
        unsigned* ebuf   = (unsigned*)d_ws + xh_words;
        unsigned* gcount = ebuf + (size_t)nbins * C;
        unsigned* ocur   = gcount + MAXBINS;
        float*    facc   = (float*)(ocur + 16);
        uint2*    ovf    = (uint2*)(gcount + META2);

        zero32_k<<<(META2 + 255) / 256, 256, 0, stream>>>(gcount, META2);
        scat2_k<<<SC2_BLOCKS, SC2_THREADS, 0, stream>>>(xm, N, xh, src, dst, E, NQ, QPB,
                                                        gcount, ebuf, (int)C, nbins, ovf, ocur);
        accum2_k<<<nbins, AC_BLOCK, 0, stream>>>(xm, xh, ebuf, gcount, (int)C, ocur, ovf,
                                                 H, W, facc, N);
        finalize_k<<<1, 64, 0, stream>>>(facc, xg, gW, gb, mW, mb, out);
    } else if (ok2) {
        uint4*    xh      = (uint4*)d_ws;
        unsigned* ebuf    = (unsigned*)d_ws + xh_words;
        unsigned* hist    = ebuf + (size_t)E;
        unsigned* offsets = hist + MAXBINS;
        unsigned* gfill   = offsets + MAXBINS + 1;
        float*    facc    = (float*)(gfill + MAXBINS);

        zero32_k<<<(int)((meta_words2 + 255) / 256), 256, 0, stream>>>(hist, (int)meta_words2);
        prep_k<<<1024, 256, 0, stream>>>(xm, N, xh, dst, E, hist, nbins);
        scan_k<<<1, MAXBINS, 0, stream>>>(hist, offsets, gfill, nbins);
        scatter_k<<<(E + SC_EPB - 1) / SC_EPB, SC_BLOCK, 0, stream>>>(src, dst, E, gfill, ebuf, nbins);
        accum_node_k<<<nbins, AC_BLOCK, 0, stream>>>(xm, xh, ebuf, offsets, H, W, facc, N);
        finalize_k<<<1, 64, 0, stream>>>(facc, xg, gW, gb, mW, mb, out);
    } else {
        float* neigh = (float*)d_ws;
        float* facc  = neigh + (size_t)N * TDIM;
        int zn = N * TDIM + 16;
        fb_zero_k<<<(zn + 255) / 256, 256, 0, stream>>>(neigh, zn);
        fb_edge_scatter_k<<<(E + 255) / 256, 256, 0, stream>>>(xm, src, dst, neigh, E);
        fb_node_k<<<256, 256, 0, stream>>>(xm, neigh, H, W, facc, N);
        finalize_k<<<1, 64, 0, stream>>>(facc, xg, gW, gb, mW, mb, out);
    }
}